// Round 1
// 169.751 us; speedup vs baseline: 1.0028x; 1.0028x over previous
//
#include <hip/hip_runtime.h>
#include <math.h>

#define NS 131072
#define EPSF 1e-8f

// workspace float offsets
#define OFF_IMP    8388608u  // 16*2048
#define OFF_VG     8421376u  // 8*2048
#define OFF_DW     8437760u  // 131072 deformation ch0 weight
#define OFF_FV     8568832u  // 4*16*128 routed frames
#define OFF_NORM   8577024u  // 32 res sumsq
#define OFF_MIX0   8577064u  // 16
#define OFF_MIX1   8577080u  // 16
#define OFF_GABS   8577096u  // 16
#define OFF_PART   8578560u  // 32*512 per-block norm partials
#define OFF_GSSP   8594944u  // 8*8 gauss sumsq partials

// ushort offsets
#define AFRAG_USH  4194304u  // imp A-frags [16 r][65 sc][64 lane][8]
#define ABF2_USH   4726784u  // fv-Toeplitz A-frags [16r][4e][8mt][4kt][64][8]
#define HB_USH     8388608u  // H bf16 [32 rx][131072]

typedef __attribute__((ext_vector_type(8))) short short8;
typedef __attribute__((ext_vector_type(4))) float floatx4;
typedef __attribute__((ext_vector_type(4))) unsigned short ushort4v;

#define INV2PI 0.15915494309189535f

__device__ __forceinline__ float sigmf(float x) { return 1.0f / (1.0f + expf(-x)); }

__device__ __forceinline__ unsigned short f2bf(float x) {
  unsigned u = __float_as_uint(x);
  unsigned r = (u + 0x7FFFu + ((u >> 16) & 1u)) >> 16;
  return (unsigned short)r;
}

// ---------------- K01: blocks<512: zero out-sum, dw, fv/before, abf2, (block0: mixes/gains);
//                  blocks 512-575: gauss -> gss partials;
//                  blocks >=576: DHO chain (self-computed params) -> res bf16 + norm partials
// pf LDS layout (DHO branch): [0..6) -gam | [6..12) amp*x0 | [12..18) gam*amp*x0 |
//   [18..24) infl*ln10 | [24..26) B1p | [26..28) om1/2pi | [28..32) Wf | [33..36) w3
__global__ __launch_bounds__(256) void k01_prep_dho(
    const float* __restrict__ csig, const float* __restrict__ deform,
    const float* __restrict__ ddmp, const float* __restrict__ dmas,
    const float* __restrict__ dten, const float* __restrict__ ddisp,
    const float* __restrict__ damp, const float* __restrict__ infl,
    const float* __restrict__ smix, const float* __restrict__ router,
    const float* __restrict__ lmix, const float* __restrict__ gains,
    const float* __restrict__ means, const float* __restrict__ stds,
    const float* __restrict__ amps, const float* __restrict__ pos,
    float* __restrict__ wsf, unsigned short* __restrict__ abf2,
    unsigned short* __restrict__ resb, float* __restrict__ partials,
    float* __restrict__ out)
{
  int tid = threadIdx.x;
  int bid = blockIdx.x;
  if (bid < 512) {
    int t = bid * 256 + tid;
    { // zero the atomically-accumulated output region
      float4 z = {0.f, 0.f, 0.f, 0.f};
      *(float4*)&out[(size_t)t * 4] = z;
    }
    { // deformation softmax + interp weight ch0
      float src = (t + 0.5f) * (1.0f / 1024.0f) - 0.5f;
      src = fminf(fmaxf(src, 0.0f), 127.0f);
      int lo = (int)src;
      int hi = min(lo + 1, 127);
      float w = src - (float)lo;
      float c0l = 1.0f / (1.0f + expf(deform[128 + lo] - (1.0f + deform[lo])));
      float c0h = 1.0f / (1.0f + expf(deform[128 + hi] - (1.0f + deform[hi])));
      wsf[OFF_DW + t] = c0l * (1.0f - w) + c0h * w;
    }
    int mt = bid & 7, e = (bid >> 3) & 3, r = (bid >> 5) & 15;
    __shared__ float fvrow[128];
    if (tid < 128) {
      float s = 0.f;
      for (int c = 0; c < 16; ++c)
        s += csig[(e * 16 + c) * 128 + tid] * router[c * 16 + r];
      fvrow[tid] = s;
      if (mt == 0) {
        wsf[OFF_FV + (e * 16 + r) * 128 + tid] = s;
        out[524288 + (e * 16 + r) * 128 + tid] = s;   // 'before'
      }
    }
    __syncthreads();
    {
      int gid = bid * 256 + tid;
      int lane = gid & 63;
      int kt = (gid >> 6) & 3;
      int m = lane & 15, quad = lane >> 4;
      int base = mt * 16 + m - kt * 32 - quad * 8;
      short8 v;
#pragma unroll
      for (int j = 0; j < 8; ++j) {
        int f = base - j;
        unsigned short b = 0;
        if (f >= 0 && f < 128) b = f2bf(fvrow[f]);
        v[j] = (short)b;
      }
      *(short8*)&abf2[(size_t)gid * 8] = v;
    }
    if (bid == 0 && tid < 16) {
      int r2 = tid;
      float l0 = lmix[r2 * 2], l1 = lmix[r2 * 2 + 1];
      float mx = fmaxf(l0, l1);
      float e0 = expf(l0 - mx), e1 = expf(l1 - mx), inv = 1.0f / (e0 + e1);
      wsf[OFF_MIX0 + r2] = e0 * inv;
      wsf[OFF_MIX1 + r2] = e1 * inv;
      wsf[OFF_GABS + r2] = fabsf(gains[r2]);
    }
  } else if (bid < 576) {                // gauss: 64 blocks
    int gb = bid - 512;
    int g = gb >> 3;
    int i = (gb & 7) * 256 + tid;
    __shared__ float kS[16], rateS[16], logAS[16], aS[16];
    __shared__ int dS[16];
    __shared__ float red[4];
    if (tid < 16) {
      int c = tid, idx = c * 8 + g;
      double m = fabs((double)means[idx]);
      double s = fabs((double)stds[idx]);
      double k = m / (s + 1e-8); k = k * k;
      double rate = m / (s * s + 1e-8);
      double logA = k * log(rate + 1e-8) - lgamma(k);
      kS[c] = (float)k; rateS[c] = (float)rate; logAS[c] = (float)logA;
      aS[c] = fabsf(amps[idx]);
      int d = 0;
      for (int l = 0; l < 11; ++l) {
        float p0 = pos[(idx * 11 + l) * 2], p1 = pos[(idx * 11 + l) * 2 + 1];
        d = d * 2 + (p1 > p0 ? 1 : 0);
      }
      dS[c] = d;
    }
    __syncthreads();
    const float step = (float)((1.0 - 1e-8) / 2047.0);
    float v = 0.f;
    for (int c = 0; c < 16; ++c) {
      int mi = i - dS[c];
      if (mi >= 0) {
        float tm = 1e-8f + (float)mi * step;
        float lp = logAS[c] + (kS[c] - 1.0f) * __logf(tm) - rateS[c] * tm;
        v += aS[c] * __expf(lp);
      }
    }
    wsf[OFF_VG + g * 2048 + i] = v;
    float sumsq = v * v;
#pragma unroll
    for (int off = 32; off; off >>= 1) sumsq += __shfl_down(sumsq, off, 64);
    if ((tid & 63) == 0) red[tid >> 6] = sumsq;
    __syncthreads();
    if (tid == 0) wsf[OFF_GSSP + gb] = red[0] + red[1] + red[2] + red[3];
  } else {                               // DHO: 16384 blocks
    int b = bid - 576;
    int rx = b >> 9;
    int t = (b & 511) * 256 + tid;
    int r = rx >> 1, x = rx & 1;
    __shared__ float pf[40];             // [33..36) = stack softmax w3 (no overlap w/ Wf)
    __shared__ float bred[4];
    if (tid < 6) {
      int ent = tid, bb = ent >> 1, o = ent & 1;
      int id = ((bb * 2 + o) * 16 + r) * 2 + x;
      float mass = 2.0f * sigmf(dmas[id]);
      float gam = 30.0f * sigmf(ddmp[id]) / (2.0f * mass);
      double W = exp((double)dten[id] * 2.302585092994046) / (double)mass;
      float x0v = ddisp[id];
      float ampv = damp[id];
      float infv = 0.f;
      if (bb == 1) infv = infl[(o * 16 + r) * 2 + x];
      if (bb == 2) infv = infl[((2 + o) * 16 + r) * 2 + x];
      pf[0 + ent]  = -gam;
      pf[6 + ent]  = ampv * x0v;
      pf[12 + ent] = gam * ampv * x0v;
      pf[18 + ent] = infv * 2.3025851f;
      if (bb == 0) {
        double om = sqrt(W - (double)gam * (double)gam);
        pf[24 + o] = (float)((double)(gam * x0v * ampv) / om);
        pf[26 + o] = (float)(om * 0.15915494309189535);
      } else {
        pf[28 + ent - 2] = (float)W;
      }
    }
    if (tid == 8) {
      float a0 = smix[rx * 3], a1 = smix[rx * 3 + 1], a2 = smix[rx * 3 + 2];
      float mm = fmaxf(a0, fmaxf(a1, a2));
      float e0 = expf(a0 - mm), e1 = expf(a1 - mm), e2 = expf(a2 - mm);
      float inv = 1.0f / (e0 + e1 + e2);
      pf[33] = e0 * inv; pf[34] = e1 * inv; pf[35] = e2 * inv;
    }
    __syncthreads();
    float ttf = (float)t * (10.0f / 131071.0f);
    float o1v = 0.f;
#pragma unroll
    for (int o = 0; o < 2; ++o) {
      float fr = pf[26 + o] * ttf;
      fr -= rintf(fr);
      float sn = __builtin_amdgcn_sinf(fr);
      float cn = __builtin_amdgcn_cosf(fr);
      float ex = __expf(pf[o] * ttf);
      o1v += ex * (pf[6 + o] * cn + pf[24 + o] * sn);
    }
    float prev = o1v, o2v = 0.f, o3v = 0.f;
#pragma unroll
    for (int blk = 1; blk < 3; ++blk) {
      float acc = 0.f;
#pragma unroll
      for (int oo = 0; oo < 2; ++oo) {
        int o = blk * 2 + oo;
        float ng = pf[o];
        float p10 = __expf(prev * pf[18 + o]);
        float rad = __builtin_fmaf(pf[28 + o - 2], p10, -(ng * ng));
        float om = __builtin_amdgcn_sqrtf(rad);
        float fr = (om * INV2PI) * ttf;
        fr -= rintf(fr);
        float sn = __builtin_amdgcn_sinf(fr);
        float cn = __builtin_amdgcn_cosf(fr);
        float Bp = pf[12 + o] * __builtin_amdgcn_rcpf(om);
        float ex = __expf(ng * ttf);
        acc += ex * (pf[6 + o] * cn + Bp * sn);
      }
      if (blk == 1) o2v = acc; else o3v = acc;
      prev = acc;
    }
    float rv = pf[33] * o1v + pf[34] * o2v + pf[35] * o3v;
    resb[(size_t)rx * NS + t] = f2bf(rv);
    float sq = rv * rv;
#pragma unroll
    for (int off = 32; off; off >>= 1) sq += __shfl_down(sq, off, 64);
    if ((tid & 63) == 0) bred[tid >> 6] = sq;
    __syncthreads();
    if (tid == 0)
      partials[rx * 512 + (b & 511)] = bred[0] + bred[1] + bred[2] + bred[3];
  }
}

// ---------------- B: blocks 0-31 norm reduce; 32-159 impulse; 160-419 abf frags (imp inline)
__global__ __launch_bounds__(256) void kB_mid(
    const float* __restrict__ ovamp, const float* __restrict__ noise,
    float* __restrict__ wsf, unsigned short* __restrict__ abf)
{
  int bid = blockIdx.x;
  int tid = threadIdx.x;
  if (bid < 32) {                        // norm reduce
    int rx = bid;
    const float* partials = wsf + OFF_PART;
    __shared__ float red[4];
    float s = partials[rx * 512 + tid] + partials[rx * 512 + 256 + tid];
#pragma unroll
    for (int off = 32; off; off >>= 1) s += __shfl_down(s, off, 64);
    if ((tid & 63) == 0) red[tid >> 6] = s;
    __syncthreads();
    if (tid == 0) wsf[OFF_NORM + rx] = red[0] + red[1] + red[2] + red[3];
    return;
  }
  __shared__ float wS[8];
  if (tid < 8) {
    float g8 = 0.f;
#pragma unroll
    for (int u = 0; u < 8; ++u) g8 += wsf[OFF_GSSP + tid * 8 + u];
    wS[tid] = 1.0f / (sqrtf(g8) + EPSF);
  }
  __syncthreads();
  const float* vg = wsf + OFF_VG;
  if (bid < 160) {                       // impulse
    int idx0 = bid - 32;
    int c = idx0 >> 3;
    int i = (idx0 & 7) * 256 + tid;
    float S = 0.f;
#pragma unroll
    for (int g = 0; g < 8; ++g) S += vg[g * 2048 + i] * wS[g];
    wsf[OFF_IMP + c * 2048 + i] = ovamp[c] * S * noise[c * 2048 + i];
    return;
  }
  // abf: imp recomputed inline
  int gid = (bid - 160) * 256 + tid;     // 16*65*64 = 66560
  if (gid >= 66560) return;
  int r = gid / (65 * 64);
  int rem = gid % (65 * 64);
  int sc = rem >> 6, lane = rem & 63;
  int m = lane & 15, quad = lane >> 4;
  int qp = (quad < 2) ? quad : quad - 4;
  int base = 32 * sc + m - 8 * qp;
  float oa = ovamp[r];
  short8 v;
#pragma unroll
  for (int j = 0; j < 8; ++j) {
    int idx = base - j;
    unsigned short b = 0;
    if (idx >= 0 && idx < 2048) {
      float S = 0.f;
#pragma unroll
      for (int g = 0; g < 8; ++g) S += vg[g * 2048 + idx] * wS[g];
      b = f2bf(oa * S * noise[r * 2048 + idx]);
    }
    v[j] = (short)b;
  }
  *(short8*)&abf[(size_t)gid * 8] = v;
}

// ---------------- K4: H via MFMA block-Toeplitz, rolling B-frag window; H stored bf16
__global__ __launch_bounds__(256) void k4_mfma(
    const unsigned short* __restrict__ resb, const unsigned short* __restrict__ abf,
    const float* __restrict__ wsf, unsigned short* __restrict__ Hb)
{
  int rx = blockIdx.y, r = rx >> 1;
  int n0 = blockIdx.x * 256;                       // 256 columns of 16 samples
  __shared__ __align__(16) unsigned short Xs[9280]; // 386 cols x stride 24
  int tid = threadIdx.x;
  for (int i = tid; i < 772; i += 256) {           // 16B chunks
    int q_rel = i >> 1, p8 = (i & 1) * 8;
    int q = n0 - 130 + q_rel;
    short8 v = {0, 0, 0, 0, 0, 0, 0, 0};
    if (q >= 0) v = *(const short8*)&resb[(size_t)rx * NS + q * 16 + p8];
    *(short8*)&Xs[q_rel * 24 + p8] = v;
  }
  __syncthreads();
  int lane = tid & 63, w = tid >> 6;
  int quad = lane >> 4, nl = lane & 15;
  float n1 = sqrtf(wsf[OFF_NORM + rx]);
  float s1 = 1.0f / (n1 + EPSF);
  float scale = s1 * (1.0f / (n1 * s1 + EPSF)) * wsf[OFF_MIX1 + r];
  const short8* af = (const short8*)(abf) + (size_t)r * 65 * 64 + lane;
  floatx4 acc0 = {0,0,0,0}, acc1 = {0,0,0,0}, acc2 = {0,0,0,0}, acc3 = {0,0,0,0};
  const char* xbase = (const char*)Xs + (size_t)(130 + w * 64 + nl - (quad >> 1)) * 48
                      + (quad & 1) * 16;
  short8 wbuf[25];
#pragma unroll
  for (int s = -24; s < 0; ++s)
    wbuf[s + 25] = *(const short8*)(xbase - 96 * s);
#pragma unroll
  for (int sc = 0; sc < 65; ++sc) {
    wbuf[sc % 25] = *(const short8*)(xbase - 96 * sc);
    short8 a = af[sc * 64];
    acc0 = __builtin_amdgcn_mfma_f32_16x16x32_bf16(a, wbuf[sc % 25],        acc0, 0, 0, 0);
    acc1 = __builtin_amdgcn_mfma_f32_16x16x32_bf16(a, wbuf[(sc + 17) % 25], acc1, 0, 0, 0);
    acc2 = __builtin_amdgcn_mfma_f32_16x16x32_bf16(a, wbuf[(sc + 9) % 25],  acc2, 0, 0, 0);
    acc3 = __builtin_amdgcn_mfma_f32_16x16x32_bf16(a, wbuf[(sc + 1) % 25],  acc3, 0, 0, 0);
  }
  unsigned short* hp = Hb + (size_t)rx * NS + 16 * (n0 + w * 64 + nl) + quad * 4;
  ushort4v h0, h1, h2, h3;
#pragma unroll
  for (int i = 0; i < 4; ++i) {
    h0[i] = f2bf(acc0[i] * scale);
    h1[i] = f2bf(acc1[i] * scale);
    h2[i] = f2bf(acc2[i] * scale);
    h3[i] = f2bf(acc3[i] * scale);
  }
  *(ushort4v*)(hp)       = h0;
  *(ushort4v*)(hp + 256) = h1;
  *(ushort4v*)(hp + 512) = h2;
  *(ushort4v*)(hp + 768) = h3;
}

// ---------------- K6: 128-tap stride conv via MFMA + deform mix + tanh reduce + cs
// NEW: cooperative LDS staging of the H tile (coalesced 64B segments, transposed
// [rx][col][136]-padded layout -> ds_read_b128 frags) + grid.z=2 mt-split for 2x occupancy.
#define HPAD 136
__global__ __launch_bounds__(256) void k6_mfma(
    const unsigned short* __restrict__ Hb, const float* __restrict__ imp,
    const unsigned short* __restrict__ abf2,
    const float* __restrict__ wsf, float* __restrict__ out)
{
  int r = blockIdx.y;
  int n0 = blockIdx.x * 32;
  int zz = blockIdx.z;                     // mt half: mt = zz*4 + wm*2 + mi
  int rm = r & 3, rq = r >> 2;
  int tid = threadIdx.x;
  int w = tid >> 6, lane = tid & 63;
  int wc = w & 1, wm = w >> 1;
  int quad = lane >> 4, n = lane & 15;
  int cl = wc * 16 + n;
  int col = n0 + cl;                       // t' in [0,1024)

  __shared__ float fvs[4][128];
  __shared__ __align__(16) unsigned short hs[2 * 32 * HPAD];  // [rx][cl][HPAD]
  for (int i = tid; i < 512; i += 256)
    fvs[i >> 7][i & 127] = wsf[OFF_FV + ((i >> 7) * 16 + r) * 128 + (i & 127)];
  {
    // one thread = one (rx,p) 64-byte segment of H, written transposed to LDS
    int rxs = tid >> 7, p = tid & 127;
    const unsigned short* src = Hb + (size_t)(2 * r + rxs) * NS + (size_t)p * 1024 + n0;
    unsigned short* dst = hs + rxs * 32 * HPAD + p;
#pragma unroll
    for (int b4 = 0; b4 < 4; ++b4) {
      short8 v = *(const short8*)(src + b4 * 8);
#pragma unroll
      for (int c = 0; c < 8; ++c)
        dst[(size_t)(b4 * 8 + c) * HPAD] = (unsigned short)v[c];
    }
  }
  __syncthreads();

  short8 bf0[4], bf1[4];
#pragma unroll
  for (int kt = 0; kt < 4; ++kt) {
    bf0[kt] = *(const short8*)&hs[(0 * 32 + cl) * HPAD + kt * 32 + quad * 8];
    bf1[kt] = *(const short8*)&hs[(1 * 32 + cl) * HPAD + kt * 32 + quad * 8];
  }

  float d0r[2][4];
  const float* dwg = wsf + OFF_DW;
#pragma unroll
  for (int mi = 0; mi < 2; ++mi)
#pragma unroll
    for (int i = 0; i < 4; ++i) {
      int q = (zz * 4 + wm * 2 + mi) * 16 + quad * 4 + i;
      d0r[mi][i] = dwg[q * 1024 + col];
    }

  float impA = imp[r * 2048 + col];
  float impB = imp[r * 2048 + 1024 + col];
  float mix0r = wsf[OFF_MIX0 + r];

  float tansum[2][4], csum[2][4];
#pragma unroll
  for (int mi = 0; mi < 2; ++mi)
#pragma unroll
    for (int i = 0; i < 4; ++i) { tansum[mi][i] = 0.f; csum[mi][i] = 0.f; }

  const short8* af = (const short8*)abf2;
  for (int e = 0; e < 4; ++e) {
    float ge = wsf[OFF_GABS + 4 * e + rq];
    const short8* afe = af + ((size_t)(r * 4 + e) * 32) * 64 + lane;
#pragma unroll
    for (int mi = 0; mi < 2; ++mi) {
      int mt = zz * 4 + wm * 2 + mi;
      floatx4 acc0 = {0, 0, 0, 0}, acc1 = {0, 0, 0, 0};
#pragma unroll
      for (int kt = 0; kt < 4; ++kt) {
        short8 a = afe[(mt * 4 + kt) * 64];
        acc0 = __builtin_amdgcn_mfma_f32_16x16x32_bf16(a, bf0[kt], acc0, 0, 0, 0);
        acc1 = __builtin_amdgcn_mfma_f32_16x16x32_bf16(a, bf1[kt], acc1, 0, 0, 0);
      }
#pragma unroll
      for (int i = 0; i < 4; ++i) {
        int q = mt * 16 + quad * 4 + i;
        float fq = fvs[e][q];
        float fqm = (q > 0) ? fvs[e][q - 1] : 0.f;
        float rsv = fq * impA + fqm * impB;
        csum[mi][i] += rsv;
        float d0 = d0r[mi][i];
        float conv = d0 * acc0[i] + (1.0f - d0) * acc1[i];
        float z = (mix0r * rsv + conv) * ge;
        float e2 = __expf(2.0f * z);
        tansum[mi][i] += 1.0f - 2.0f * __builtin_amdgcn_rcpf(e2 + 1.0f);
      }
    }
  }
#pragma unroll
  for (int mi = 0; mi < 2; ++mi)
#pragma unroll
    for (int i = 0; i < 4; ++i) {
      int q = (zz * 4 + wm * 2 + mi) * 16 + quad * 4 + i;
      atomicAdd(&out[(size_t)rm * NS + q * 1024 + col], tansum[mi][i]);
      out[532480 + (size_t)r * NS + q * 1024 + col] = csum[mi][i];
    }
}

extern "C" void kernel_launch(void* const* d_in, const int* in_sizes, int n_in,
                              void* d_out, int out_size, void* d_ws, size_t ws_size,
                              hipStream_t stream) {
  const float* csig   = (const float*)d_in[0];
  const float* deform = (const float*)d_in[1];
  const float* aem    = (const float*)d_in[2];
  const float* aes    = (const float*)d_in[3];
  const float* aea    = (const float*)d_in[4];
  const float* aep    = (const float*)d_in[5];
  const float* aeo    = (const float*)d_in[6];
  const float* ddmp   = (const float*)d_in[7];
  const float* dmas   = (const float*)d_in[8];
  const float* dten   = (const float*)d_in[9];
  const float* ddisp  = (const float*)d_in[10];
  const float* damp   = (const float*)d_in[11];
  const float* infl   = (const float*)d_in[12];
  const float* smix   = (const float*)d_in[13];
  const float* router = (const float*)d_in[14];
  const float* lmix   = (const float*)d_in[15];
  const float* gains  = (const float*)d_in[16];
  const float* anoise = (const float*)d_in[17];

  float*  wsf = (float*)d_ws;
  unsigned short* resb = (unsigned short*)d_ws;
  unsigned short* abf  = (unsigned short*)d_ws + AFRAG_USH;
  unsigned short* abf2 = (unsigned short*)d_ws + ABF2_USH;
  unsigned short* Hb   = (unsigned short*)d_ws + HB_USH;
  float*  out = (float*)d_out;

  k01_prep_dho<<<16960, 256, 0, stream>>>(csig, deform, ddmp, dmas, dten, ddisp,
                                          damp, infl, smix, router, lmix, gains,
                                          aem, aes, aea, aep, wsf, abf2, resb,
                                          wsf + OFF_PART, out);
  kB_mid<<<420, 256, 0, stream>>>(aeo, anoise, wsf, abf);
  k4_mfma<<<dim3(32, 32), 256, 0, stream>>>(resb, abf, wsf, Hb);
  k6_mfma<<<dim3(32, 16, 2), 256, 0, stream>>>(Hb, wsf + OFF_IMP, abf2, wsf, out);
}

// Round 2
// 164.433 us; speedup vs baseline: 1.0352x; 1.0323x over previous
//
#include <hip/hip_runtime.h>
#include <math.h>

#define NS 131072
#define EPSF 1e-8f

// workspace float offsets
#define OFF_IMP    8388608u  // 16*2048
#define OFF_VG     8421376u  // 8*2048
#define OFF_DW     8437760u  // 131072 deformation ch0 weight
#define OFF_FV     8568832u  // 4*16*128 routed frames
#define OFF_NORM   8577024u  // 32 res sumsq
#define OFF_MIX0   8577064u  // 16
#define OFF_MIX1   8577080u  // 16
#define OFF_GABS   8577096u  // 16
#define OFF_PART   8578560u  // 32*512 per-block norm partials (256 used/rx)
#define OFF_GSSP   8594944u  // 8*8 gauss sumsq partials
#define OFF_DHP    8595200u  // 32*40 precomputed DHO params

// ushort offsets
#define AFRAG_USH  4194304u  // imp A-frags [16 r][65 sc][64 lane][8]
#define ABF2_USH   4726784u  // fv-Toeplitz A-frags [16r][4e][8mt][4kt][64][8]
#define HB_USH     8388608u  // H bf16 [32 rx][131072]

typedef __attribute__((ext_vector_type(8))) short short8;
typedef __attribute__((ext_vector_type(4))) float floatx4;
typedef __attribute__((ext_vector_type(4))) unsigned short ushort4v;

#define INV2PI 0.15915494309189535f

__device__ __forceinline__ float sigmf(float x) { return 1.0f / (1.0f + expf(-x)); }

__device__ __forceinline__ unsigned short f2bf(float x) {
  unsigned u = __float_as_uint(x);
  unsigned r = (u + 0x7FFFu + ((u >> 16) & 1u)) >> 16;
  return (unsigned short)r;
}

// ---------------- K0: one block computes all 32 rx DHO params (layout matches pf[])
// pf layout per rx: [0..6) -gam | [6..12) amp*x0 | [12..18) gam*amp*x0 |
//   [18..24) infl*ln10 | [24..26) B1p | [26..28) om1/2pi | [28..32) Wf | [33..36) w3
__global__ __launch_bounds__(256) void k0_params(
    const float* __restrict__ ddmp, const float* __restrict__ dmas,
    const float* __restrict__ dten, const float* __restrict__ ddisp,
    const float* __restrict__ damp, const float* __restrict__ infl,
    const float* __restrict__ smix, float* __restrict__ wsf)
{
  int tid = threadIdx.x;
  int rx = tid >> 3, ent = tid & 7;
  int r = rx >> 1, x = rx & 1;
  float* g = wsf + OFF_DHP + rx * 40;
  if (ent < 6) {
    int bb = ent >> 1, o = ent & 1;
    int id = ((bb * 2 + o) * 16 + r) * 2 + x;
    float mass = 2.0f * sigmf(dmas[id]);
    float gam = 30.0f * sigmf(ddmp[id]) / (2.0f * mass);
    double W = exp((double)dten[id] * 2.302585092994046) / (double)mass;
    float x0v = ddisp[id];
    float ampv = damp[id];
    float infv = 0.f;
    if (bb == 1) infv = infl[(o * 16 + r) * 2 + x];
    if (bb == 2) infv = infl[((2 + o) * 16 + r) * 2 + x];
    g[0 + ent]  = -gam;
    g[6 + ent]  = ampv * x0v;
    g[12 + ent] = gam * ampv * x0v;
    g[18 + ent] = infv * 2.3025851f;
    if (bb == 0) {
      double om = sqrt(W - (double)gam * (double)gam);
      g[24 + o] = (float)((double)(gam * x0v * ampv) / om);
      g[26 + o] = (float)(om * 0.15915494309189535);
    } else {
      g[28 + ent - 2] = (float)W;
    }
    // init unused slots to keep poisoned ws out of LDS
    if (ent == 0) { g[32] = 0.f; g[36] = 0.f; g[37] = 0.f; g[38] = 0.f; g[39] = 0.f; }
  } else if (ent == 6) {
    float a0 = smix[rx * 3], a1 = smix[rx * 3 + 1], a2 = smix[rx * 3 + 2];
    float mm = fmaxf(a0, fmaxf(a1, a2));
    float e0 = expf(a0 - mm), e1 = expf(a1 - mm), e2 = expf(a2 - mm);
    float inv = 1.0f / (e0 + e1 + e2);
    g[33] = e0 * inv; g[34] = e1 * inv; g[35] = e2 * inv;
  }
}

// ---------------- K01: blocks<512: zero out-sum, dw, fv/before, abf2, (block0: mixes/gains);
//                  blocks 512-575: gauss -> gss partials;
//                  blocks >=576: DHO chain (precomputed params) -> res bf16 + norm partials
__global__ __launch_bounds__(256) void k01_prep_dho(
    const float* __restrict__ csig, const float* __restrict__ deform,
    const float* __restrict__ smix_unused, const float* __restrict__ router,
    const float* __restrict__ lmix, const float* __restrict__ gains,
    const float* __restrict__ means, const float* __restrict__ stds,
    const float* __restrict__ amps, const float* __restrict__ pos,
    float* __restrict__ wsf, unsigned short* __restrict__ abf2,
    unsigned short* __restrict__ resb, float* __restrict__ partials,
    float* __restrict__ out)
{
  int tid = threadIdx.x;
  int bid = blockIdx.x;
  if (bid < 512) {
    int t = bid * 256 + tid;
    { // zero the atomically-accumulated output region
      float4 z = {0.f, 0.f, 0.f, 0.f};
      *(float4*)&out[(size_t)t * 4] = z;
    }
    { // deformation softmax + interp weight ch0
      float src = (t + 0.5f) * (1.0f / 1024.0f) - 0.5f;
      src = fminf(fmaxf(src, 0.0f), 127.0f);
      int lo = (int)src;
      int hi = min(lo + 1, 127);
      float w = src - (float)lo;
      float c0l = 1.0f / (1.0f + expf(deform[128 + lo] - (1.0f + deform[lo])));
      float c0h = 1.0f / (1.0f + expf(deform[128 + hi] - (1.0f + deform[hi])));
      wsf[OFF_DW + t] = c0l * (1.0f - w) + c0h * w;
    }
    int mt = bid & 7, e = (bid >> 3) & 3, r = (bid >> 5) & 15;
    __shared__ float fvrow[128];
    if (tid < 128) {
      float s = 0.f;
      for (int c = 0; c < 16; ++c)
        s += csig[(e * 16 + c) * 128 + tid] * router[c * 16 + r];
      fvrow[tid] = s;
      if (mt == 0) {
        wsf[OFF_FV + (e * 16 + r) * 128 + tid] = s;
        out[524288 + (e * 16 + r) * 128 + tid] = s;   // 'before'
      }
    }
    __syncthreads();
    {
      int gid = bid * 256 + tid;
      int lane = gid & 63;
      int kt = (gid >> 6) & 3;
      int m = lane & 15, quad = lane >> 4;
      int base = mt * 16 + m - kt * 32 - quad * 8;
      short8 v;
#pragma unroll
      for (int j = 0; j < 8; ++j) {
        int f = base - j;
        unsigned short b = 0;
        if (f >= 0 && f < 128) b = f2bf(fvrow[f]);
        v[j] = (short)b;
      }
      *(short8*)&abf2[(size_t)gid * 8] = v;
    }
    if (bid == 0 && tid < 16) {
      int r2 = tid;
      float l0 = lmix[r2 * 2], l1 = lmix[r2 * 2 + 1];
      float mx = fmaxf(l0, l1);
      float e0 = expf(l0 - mx), e1 = expf(l1 - mx), inv = 1.0f / (e0 + e1);
      wsf[OFF_MIX0 + r2] = e0 * inv;
      wsf[OFF_MIX1 + r2] = e1 * inv;
      wsf[OFF_GABS + r2] = fabsf(gains[r2]);
    }
  } else if (bid < 576) {                // gauss: 64 blocks
    int gb = bid - 512;
    int g = gb >> 3;
    int i = (gb & 7) * 256 + tid;
    __shared__ float kS[16], rateS[16], logAS[16], aS[16];
    __shared__ int dS[16];
    __shared__ float red[4];
    if (tid < 16) {
      int c = tid, idx = c * 8 + g;
      double m = fabs((double)means[idx]);
      double s = fabs((double)stds[idx]);
      double k = m / (s + 1e-8); k = k * k;
      double rate = m / (s * s + 1e-8);
      double logA = k * log(rate + 1e-8) - lgamma(k);
      kS[c] = (float)k; rateS[c] = (float)rate; logAS[c] = (float)logA;
      aS[c] = fabsf(amps[idx]);
      int d = 0;
      for (int l = 0; l < 11; ++l) {
        float p0 = pos[(idx * 11 + l) * 2], p1 = pos[(idx * 11 + l) * 2 + 1];
        d = d * 2 + (p1 > p0 ? 1 : 0);
      }
      dS[c] = d;
    }
    __syncthreads();
    const float step = (float)((1.0 - 1e-8) / 2047.0);
    float v = 0.f;
    for (int c = 0; c < 16; ++c) {
      int mi = i - dS[c];
      if (mi >= 0) {
        float tm = 1e-8f + (float)mi * step;
        float lp = logAS[c] + (kS[c] - 1.0f) * __logf(tm) - rateS[c] * tm;
        v += aS[c] * __expf(lp);
      }
    }
    wsf[OFF_VG + g * 2048 + i] = v;
    float sumsq = v * v;
#pragma unroll
    for (int off = 32; off; off >>= 1) sumsq += __shfl_down(sumsq, off, 64);
    if ((tid & 63) == 0) red[tid >> 6] = sumsq;
    __syncthreads();
    if (tid == 0) wsf[OFF_GSSP + gb] = red[0] + red[1] + red[2] + red[3];
  } else {                               // DHO: 8192 blocks, 2 samples/thread
    int b = bid - 576;
    int rx = b >> 8;
    int t0 = (b & 255) * 512 + tid * 2;
    __shared__ float pf[40];
    __shared__ float bred[4];
    if (tid < 40) pf[tid] = wsf[OFF_DHP + rx * 40 + tid];
    __syncthreads();
    float sqacc = 0.f;
    unsigned short h2[2];
#pragma unroll
    for (int u = 0; u < 2; ++u) {
      float ttf = (float)(t0 + u) * (10.0f / 131071.0f);
      float o1v = 0.f;
#pragma unroll
      for (int o = 0; o < 2; ++o) {
        float fr = pf[26 + o] * ttf;
        fr -= rintf(fr);
        float sn = __builtin_amdgcn_sinf(fr);
        float cn = __builtin_amdgcn_cosf(fr);
        float ex = __expf(pf[o] * ttf);
        o1v += ex * (pf[6 + o] * cn + pf[24 + o] * sn);
      }
      float prev = o1v, o2v = 0.f, o3v = 0.f;
#pragma unroll
      for (int blk = 1; blk < 3; ++blk) {
        float acc = 0.f;
#pragma unroll
        for (int oo = 0; oo < 2; ++oo) {
          int o = blk * 2 + oo;
          float ng = pf[o];
          float p10 = __expf(prev * pf[18 + o]);
          float rad = __builtin_fmaf(pf[28 + o - 2], p10, -(ng * ng));
          float om = __builtin_amdgcn_sqrtf(rad);
          float fr = (om * INV2PI) * ttf;
          fr -= rintf(fr);
          float sn = __builtin_amdgcn_sinf(fr);
          float cn = __builtin_amdgcn_cosf(fr);
          float Bp = pf[12 + o] * __builtin_amdgcn_rcpf(om);
          float ex = __expf(ng * ttf);
          acc += ex * (pf[6 + o] * cn + Bp * sn);
        }
        if (blk == 1) o2v = acc; else o3v = acc;
        prev = acc;
      }
      float rv = pf[33] * o1v + pf[34] * o2v + pf[35] * o3v;
      h2[u] = f2bf(rv);
      sqacc += rv * rv;
    }
    *(unsigned*)&resb[(size_t)rx * NS + t0] =
        (unsigned)h2[0] | ((unsigned)h2[1] << 16);
#pragma unroll
    for (int off = 32; off; off >>= 1) sqacc += __shfl_down(sqacc, off, 64);
    if ((tid & 63) == 0) bred[tid >> 6] = sqacc;
    __syncthreads();
    if (tid == 0)
      partials[rx * 512 + (b & 255)] = bred[0] + bred[1] + bred[2] + bred[3];
  }
}

// ---------------- B: blocks 0-31 norm reduce; 32-159 impulse; 160-419 abf frags (imp inline)
__global__ __launch_bounds__(256) void kB_mid(
    const float* __restrict__ ovamp, const float* __restrict__ noise,
    float* __restrict__ wsf, unsigned short* __restrict__ abf)
{
  int bid = blockIdx.x;
  int tid = threadIdx.x;
  if (bid < 32) {                        // norm reduce (256 partials per rx)
    int rx = bid;
    const float* partials = wsf + OFF_PART;
    __shared__ float red[4];
    float s = partials[rx * 512 + tid];
#pragma unroll
    for (int off = 32; off; off >>= 1) s += __shfl_down(s, off, 64);
    if ((tid & 63) == 0) red[tid >> 6] = s;
    __syncthreads();
    if (tid == 0) wsf[OFF_NORM + rx] = red[0] + red[1] + red[2] + red[3];
    return;
  }
  __shared__ float wS[8];
  if (tid < 8) {
    float g8 = 0.f;
#pragma unroll
    for (int u = 0; u < 8; ++u) g8 += wsf[OFF_GSSP + tid * 8 + u];
    wS[tid] = 1.0f / (sqrtf(g8) + EPSF);
  }
  __syncthreads();
  const float* vg = wsf + OFF_VG;
  if (bid < 160) {                       // impulse
    int idx0 = bid - 32;
    int c = idx0 >> 3;
    int i = (idx0 & 7) * 256 + tid;
    float S = 0.f;
#pragma unroll
    for (int g = 0; g < 8; ++g) S += vg[g * 2048 + i] * wS[g];
    wsf[OFF_IMP + c * 2048 + i] = ovamp[c] * S * noise[c * 2048 + i];
    return;
  }
  // abf: imp recomputed inline
  int gid = (bid - 160) * 256 + tid;     // 16*65*64 = 66560
  if (gid >= 66560) return;
  int r = gid / (65 * 64);
  int rem = gid % (65 * 64);
  int sc = rem >> 6, lane = rem & 63;
  int m = lane & 15, quad = lane >> 4;
  int qp = (quad < 2) ? quad : quad - 4;
  int base = 32 * sc + m - 8 * qp;
  float oa = ovamp[r];
  short8 v;
#pragma unroll
  for (int j = 0; j < 8; ++j) {
    int idx = base - j;
    unsigned short b = 0;
    if (idx >= 0 && idx < 2048) {
      float S = 0.f;
#pragma unroll
      for (int g = 0; g < 8; ++g) S += vg[g * 2048 + idx] * wS[g];
      b = f2bf(oa * S * noise[r * 2048 + idx]);
    }
    v[j] = (short)b;
  }
  *(short8*)&abf[(size_t)gid * 8] = v;
}

// ---------------- K4: H via MFMA block-Toeplitz, rolling B-frag window; H stored bf16
__global__ __launch_bounds__(256) void k4_mfma(
    const unsigned short* __restrict__ resb, const unsigned short* __restrict__ abf,
    const float* __restrict__ wsf, unsigned short* __restrict__ Hb)
{
  int rx = blockIdx.y, r = rx >> 1;
  int n0 = blockIdx.x * 256;                       // 256 columns of 16 samples
  __shared__ __align__(16) unsigned short Xs[9280]; // 386 cols x stride 24
  int tid = threadIdx.x;
  for (int i = tid; i < 772; i += 256) {           // 16B chunks
    int q_rel = i >> 1, p8 = (i & 1) * 8;
    int q = n0 - 130 + q_rel;
    short8 v = {0, 0, 0, 0, 0, 0, 0, 0};
    if (q >= 0) v = *(const short8*)&resb[(size_t)rx * NS + q * 16 + p8];
    *(short8*)&Xs[q_rel * 24 + p8] = v;
  }
  __syncthreads();
  int lane = tid & 63, w = tid >> 6;
  int quad = lane >> 4, nl = lane & 15;
  float n1 = sqrtf(wsf[OFF_NORM + rx]);
  float s1 = 1.0f / (n1 + EPSF);
  float scale = s1 * (1.0f / (n1 * s1 + EPSF)) * wsf[OFF_MIX1 + r];
  const short8* af = (const short8*)(abf) + (size_t)r * 65 * 64 + lane;
  floatx4 acc0 = {0,0,0,0}, acc1 = {0,0,0,0}, acc2 = {0,0,0,0}, acc3 = {0,0,0,0};
  const char* xbase = (const char*)Xs + (size_t)(130 + w * 64 + nl - (quad >> 1)) * 48
                      + (quad & 1) * 16;
  short8 wbuf[25];
#pragma unroll
  for (int s = -24; s < 0; ++s)
    wbuf[s + 25] = *(const short8*)(xbase - 96 * s);
#pragma unroll
  for (int sc = 0; sc < 65; ++sc) {
    wbuf[sc % 25] = *(const short8*)(xbase - 96 * sc);
    short8 a = af[sc * 64];
    acc0 = __builtin_amdgcn_mfma_f32_16x16x32_bf16(a, wbuf[sc % 25],        acc0, 0, 0, 0);
    acc1 = __builtin_amdgcn_mfma_f32_16x16x32_bf16(a, wbuf[(sc + 17) % 25], acc1, 0, 0, 0);
    acc2 = __builtin_amdgcn_mfma_f32_16x16x32_bf16(a, wbuf[(sc + 9) % 25],  acc2, 0, 0, 0);
    acc3 = __builtin_amdgcn_mfma_f32_16x16x32_bf16(a, wbuf[(sc + 1) % 25],  acc3, 0, 0, 0);
  }
  unsigned short* hp = Hb + (size_t)rx * NS + 16 * (n0 + w * 64 + nl) + quad * 4;
  ushort4v h0, h1, h2, h3;
#pragma unroll
  for (int i = 0; i < 4; ++i) {
    h0[i] = f2bf(acc0[i] * scale);
    h1[i] = f2bf(acc1[i] * scale);
    h2[i] = f2bf(acc2[i] * scale);
    h3[i] = f2bf(acc3[i] * scale);
  }
  *(ushort4v*)(hp)       = h0;
  *(ushort4v*)(hp + 256) = h1;
  *(ushort4v*)(hp + 512) = h2;
  *(ushort4v*)(hp + 768) = h3;
}

// ---------------- K6: 128-tap stride conv via MFMA + deform mix + tanh reduce + cs
#define HPAD 136
__global__ __launch_bounds__(256) void k6_mfma(
    const unsigned short* __restrict__ Hb, const float* __restrict__ imp,
    const unsigned short* __restrict__ abf2,
    const float* __restrict__ wsf, float* __restrict__ out)
{
  int r = blockIdx.y;
  int n0 = blockIdx.x * 32;
  int zz = blockIdx.z;                     // mt half: mt = zz*4 + wm*2 + mi
  int rm = r & 3, rq = r >> 2;
  int tid = threadIdx.x;
  int w = tid >> 6, lane = tid & 63;
  int wc = w & 1, wm = w >> 1;
  int quad = lane >> 4, n = lane & 15;
  int cl = wc * 16 + n;
  int col = n0 + cl;                       // t' in [0,1024)

  __shared__ float fvs[4][128];
  __shared__ __align__(16) unsigned short hs[2 * 32 * HPAD];  // [rx][cl][HPAD]
  for (int i = tid; i < 512; i += 256)
    fvs[i >> 7][i & 127] = wsf[OFF_FV + ((i >> 7) * 16 + r) * 128 + (i & 127)];
  {
    // one thread = one (rx,p) 64-byte segment of H, written transposed to LDS
    int rxs = tid >> 7, p = tid & 127;
    const unsigned short* src = Hb + (size_t)(2 * r + rxs) * NS + (size_t)p * 1024 + n0;
    unsigned short* dst = hs + rxs * 32 * HPAD + p;
#pragma unroll
    for (int b4 = 0; b4 < 4; ++b4) {
      short8 v = *(const short8*)(src + b4 * 8);
#pragma unroll
      for (int c = 0; c < 8; ++c)
        dst[(size_t)(b4 * 8 + c) * HPAD] = (unsigned short)v[c];
    }
  }
  __syncthreads();

  short8 bf0[4], bf1[4];
#pragma unroll
  for (int kt = 0; kt < 4; ++kt) {
    bf0[kt] = *(const short8*)&hs[(0 * 32 + cl) * HPAD + kt * 32 + quad * 8];
    bf1[kt] = *(const short8*)&hs[(1 * 32 + cl) * HPAD + kt * 32 + quad * 8];
  }

  float d0r[2][4];
  const float* dwg = wsf + OFF_DW;
#pragma unroll
  for (int mi = 0; mi < 2; ++mi)
#pragma unroll
    for (int i = 0; i < 4; ++i) {
      int q = (zz * 4 + wm * 2 + mi) * 16 + quad * 4 + i;
      d0r[mi][i] = dwg[q * 1024 + col];
    }

  float impA = imp[r * 2048 + col];
  float impB = imp[r * 2048 + 1024 + col];
  float mix0r = wsf[OFF_MIX0 + r];

  float tansum[2][4], csum[2][4];
#pragma unroll
  for (int mi = 0; mi < 2; ++mi)
#pragma unroll
    for (int i = 0; i < 4; ++i) { tansum[mi][i] = 0.f; csum[mi][i] = 0.f; }

  const short8* af = (const short8*)abf2;
  for (int e = 0; e < 4; ++e) {
    float ge = wsf[OFF_GABS + 4 * e + rq];
    const short8* afe = af + ((size_t)(r * 4 + e) * 32) * 64 + lane;
#pragma unroll
    for (int mi = 0; mi < 2; ++mi) {
      int mt = zz * 4 + wm * 2 + mi;
      floatx4 acc0 = {0, 0, 0, 0}, acc1 = {0, 0, 0, 0};
#pragma unroll
      for (int kt = 0; kt < 4; ++kt) {
        short8 a = afe[(mt * 4 + kt) * 64];
        acc0 = __builtin_amdgcn_mfma_f32_16x16x32_bf16(a, bf0[kt], acc0, 0, 0, 0);
        acc1 = __builtin_amdgcn_mfma_f32_16x16x32_bf16(a, bf1[kt], acc1, 0, 0, 0);
      }
#pragma unroll
      for (int i = 0; i < 4; ++i) {
        int q = mt * 16 + quad * 4 + i;
        float fq = fvs[e][q];
        float fqm = (q > 0) ? fvs[e][q - 1] : 0.f;
        float rsv = fq * impA + fqm * impB;
        csum[mi][i] += rsv;
        float d0 = d0r[mi][i];
        float conv = d0 * acc0[i] + (1.0f - d0) * acc1[i];
        float z = (mix0r * rsv + conv) * ge;
        float e2 = __expf(2.0f * z);
        tansum[mi][i] += 1.0f - 2.0f * __builtin_amdgcn_rcpf(e2 + 1.0f);
      }
    }
  }
#pragma unroll
  for (int mi = 0; mi < 2; ++mi)
#pragma unroll
    for (int i = 0; i < 4; ++i) {
      int q = (zz * 4 + wm * 2 + mi) * 16 + quad * 4 + i;
      atomicAdd(&out[(size_t)rm * NS + q * 1024 + col], tansum[mi][i]);
      out[532480 + (size_t)r * NS + q * 1024 + col] = csum[mi][i];
    }
}

extern "C" void kernel_launch(void* const* d_in, const int* in_sizes, int n_in,
                              void* d_out, int out_size, void* d_ws, size_t ws_size,
                              hipStream_t stream) {
  const float* csig   = (const float*)d_in[0];
  const float* deform = (const float*)d_in[1];
  const float* aem    = (const float*)d_in[2];
  const float* aes    = (const float*)d_in[3];
  const float* aea    = (const float*)d_in[4];
  const float* aep    = (const float*)d_in[5];
  const float* aeo    = (const float*)d_in[6];
  const float* ddmp   = (const float*)d_in[7];
  const float* dmas   = (const float*)d_in[8];
  const float* dten   = (const float*)d_in[9];
  const float* ddisp  = (const float*)d_in[10];
  const float* damp   = (const float*)d_in[11];
  const float* infl   = (const float*)d_in[12];
  const float* smix   = (const float*)d_in[13];
  const float* router = (const float*)d_in[14];
  const float* lmix   = (const float*)d_in[15];
  const float* gains  = (const float*)d_in[16];
  const float* anoise = (const float*)d_in[17];

  float*  wsf = (float*)d_ws;
  unsigned short* resb = (unsigned short*)d_ws;
  unsigned short* abf  = (unsigned short*)d_ws + AFRAG_USH;
  unsigned short* abf2 = (unsigned short*)d_ws + ABF2_USH;
  unsigned short* Hb   = (unsigned short*)d_ws + HB_USH;
  float*  out = (float*)d_out;

  k0_params<<<1, 256, 0, stream>>>(ddmp, dmas, dten, ddisp, damp, infl, smix, wsf);
  k01_prep_dho<<<8768, 256, 0, stream>>>(csig, deform, smix, router, lmix, gains,
                                         aem, aes, aea, aep, wsf, abf2, resb,
                                         wsf + OFF_PART, out);
  kB_mid<<<420, 256, 0, stream>>>(aeo, anoise, wsf, abf);
  k4_mfma<<<dim3(32, 32), 256, 0, stream>>>(resb, abf, wsf, Hb);
  k6_mfma<<<dim3(32, 16, 2), 256, 0, stream>>>(Hb, wsf + OFF_IMP, abf2, wsf, out);
}

// Round 3
// 162.961 us; speedup vs baseline: 1.0445x; 1.0090x over previous
//
#include <hip/hip_runtime.h>
#include <math.h>

#define NS 131072
#define EPSF 1e-8f

// workspace float offsets
#define OFF_IMP    8388608u  // 16*2048
#define OFF_VG     8421376u  // 8*2048
#define OFF_DW     8437760u  // 131072 deformation ch0 weight
#define OFF_FV     8568832u  // 4*16*128 routed frames
#define OFF_NORM   8577024u  // 32 res sumsq
#define OFF_MIX0   8577064u  // 16
#define OFF_MIX1   8577080u  // 16
#define OFF_GABS   8577096u  // 16
#define OFF_PART   8578560u  // 32*512 per-block norm partials (128 used/rx)
#define OFF_GSSP   8594944u  // 8*8 gauss sumsq partials
#define OFF_DHP    8595200u  // 32*40 precomputed DHO params

// ushort offsets
#define AFRAG_USH  4194304u  // imp A-frags [16 r][65 sc][64 lane][8]
#define ABF2_USH   4726784u  // fv-Toeplitz A-frags [16r][4e][8mt][4kt][64][8]
#define HB_USH     8388608u  // H bf16 [32 rx][131072]

typedef __attribute__((ext_vector_type(8))) short short8;
typedef __attribute__((ext_vector_type(4))) float floatx4;
typedef __attribute__((ext_vector_type(4))) unsigned short ushort4v;

#define INV2PI 0.15915494309189535f

__device__ __forceinline__ float sigmf(float x) { return 1.0f / (1.0f + expf(-x)); }

__device__ __forceinline__ unsigned short f2bf(float x) {
  unsigned u = __float_as_uint(x);
  unsigned r = (u + 0x7FFFu + ((u >> 16) & 1u)) >> 16;
  return (unsigned short)r;
}

// ---------------- K0: one block computes all 32 rx DHO params (layout matches pf[])
__global__ __launch_bounds__(256) void k0_params(
    const float* __restrict__ ddmp, const float* __restrict__ dmas,
    const float* __restrict__ dten, const float* __restrict__ ddisp,
    const float* __restrict__ damp, const float* __restrict__ infl,
    const float* __restrict__ smix, float* __restrict__ wsf)
{
  int tid = threadIdx.x;
  int rx = tid >> 3, ent = tid & 7;
  int r = rx >> 1, x = rx & 1;
  float* g = wsf + OFF_DHP + rx * 40;
  if (ent < 6) {
    int bb = ent >> 1, o = ent & 1;
    int id = ((bb * 2 + o) * 16 + r) * 2 + x;
    float mass = 2.0f * sigmf(dmas[id]);
    float gam = 30.0f * sigmf(ddmp[id]) / (2.0f * mass);
    double W = exp((double)dten[id] * 2.302585092994046) / (double)mass;
    float x0v = ddisp[id];
    float ampv = damp[id];
    float infv = 0.f;
    if (bb == 1) infv = infl[(o * 16 + r) * 2 + x];
    if (bb == 2) infv = infl[((2 + o) * 16 + r) * 2 + x];
    g[0 + ent]  = -gam;
    g[6 + ent]  = ampv * x0v;
    g[12 + ent] = gam * ampv * x0v;
    g[18 + ent] = infv * 2.3025851f;
    if (bb == 0) {
      double om = sqrt(W - (double)gam * (double)gam);
      g[24 + o] = (float)((double)(gam * x0v * ampv) / om);
      g[26 + o] = (float)(om * 0.15915494309189535);
    } else {
      g[28 + ent - 2] = (float)W;
    }
    if (ent == 0) { g[32] = 0.f; g[36] = 0.f; g[37] = 0.f; g[38] = 0.f; g[39] = 0.f; }
  } else if (ent == 6) {
    float a0 = smix[rx * 3], a1 = smix[rx * 3 + 1], a2 = smix[rx * 3 + 2];
    float mm = fmaxf(a0, fmaxf(a1, a2));
    float e0 = expf(a0 - mm), e1 = expf(a1 - mm), e2 = expf(a2 - mm);
    float inv = 1.0f / (e0 + e1 + e2);
    g[33] = e0 * inv; g[34] = e1 * inv; g[35] = e2 * inv;
  }
}

// ---------------- K01: blocks<512: dw, fv/before, abf2, (block0: mixes/gains);
//                  blocks 512-575: gauss -> gss partials;
//                  blocks >=576: DHO chain (precomputed params), 4 samples/thread
__global__ __launch_bounds__(256) void k01_prep_dho(
    const float* __restrict__ csig, const float* __restrict__ deform,
    const float* __restrict__ smix_unused, const float* __restrict__ router,
    const float* __restrict__ lmix, const float* __restrict__ gains,
    const float* __restrict__ means, const float* __restrict__ stds,
    const float* __restrict__ amps, const float* __restrict__ pos,
    float* __restrict__ wsf, unsigned short* __restrict__ abf2,
    unsigned short* __restrict__ resb, float* __restrict__ partials,
    float* __restrict__ out)
{
  int tid = threadIdx.x;
  int bid = blockIdx.x;
  if (bid < 512) {
    int t = bid * 256 + tid;
    { // deformation softmax + interp weight ch0
      float src = (t + 0.5f) * (1.0f / 1024.0f) - 0.5f;
      src = fminf(fmaxf(src, 0.0f), 127.0f);
      int lo = (int)src;
      int hi = min(lo + 1, 127);
      float w = src - (float)lo;
      float c0l = 1.0f / (1.0f + expf(deform[128 + lo] - (1.0f + deform[lo])));
      float c0h = 1.0f / (1.0f + expf(deform[128 + hi] - (1.0f + deform[hi])));
      wsf[OFF_DW + t] = c0l * (1.0f - w) + c0h * w;
    }
    int mt = bid & 7, e = (bid >> 3) & 3, r = (bid >> 5) & 15;
    __shared__ float fvrow[128];
    if (tid < 128) {
      float s = 0.f;
      for (int c = 0; c < 16; ++c)
        s += csig[(e * 16 + c) * 128 + tid] * router[c * 16 + r];
      fvrow[tid] = s;
      if (mt == 0) {
        wsf[OFF_FV + (e * 16 + r) * 128 + tid] = s;
        out[524288 + (e * 16 + r) * 128 + tid] = s;   // 'before'
      }
    }
    __syncthreads();
    {
      int gid = bid * 256 + tid;
      int lane = gid & 63;
      int kt = (gid >> 6) & 3;
      int m = lane & 15, quad = lane >> 4;
      int base = mt * 16 + m - kt * 32 - quad * 8;
      short8 v;
#pragma unroll
      for (int j = 0; j < 8; ++j) {
        int f = base - j;
        unsigned short b = 0;
        if (f >= 0 && f < 128) b = f2bf(fvrow[f]);
        v[j] = (short)b;
      }
      *(short8*)&abf2[(size_t)gid * 8] = v;
    }
    if (bid == 0 && tid < 16) {
      int r2 = tid;
      float l0 = lmix[r2 * 2], l1 = lmix[r2 * 2 + 1];
      float mx = fmaxf(l0, l1);
      float e0 = expf(l0 - mx), e1 = expf(l1 - mx), inv = 1.0f / (e0 + e1);
      wsf[OFF_MIX0 + r2] = e0 * inv;
      wsf[OFF_MIX1 + r2] = e1 * inv;
      wsf[OFF_GABS + r2] = fabsf(gains[r2]);
    }
  } else if (bid < 576) {                // gauss: 64 blocks
    int gb = bid - 512;
    int g = gb >> 3;
    int i = (gb & 7) * 256 + tid;
    __shared__ float kS[16], rateS[16], logAS[16], aS[16];
    __shared__ int dS[16];
    __shared__ float red[4];
    if (tid < 16) {
      int c = tid, idx = c * 8 + g;
      double m = fabs((double)means[idx]);
      double s = fabs((double)stds[idx]);
      double k = m / (s + 1e-8); k = k * k;
      double rate = m / (s * s + 1e-8);
      double logA = k * log(rate + 1e-8) - lgamma(k);
      kS[c] = (float)k; rateS[c] = (float)rate; logAS[c] = (float)logA;
      aS[c] = fabsf(amps[idx]);
      int d = 0;
      for (int l = 0; l < 11; ++l) {
        float p0 = pos[(idx * 11 + l) * 2], p1 = pos[(idx * 11 + l) * 2 + 1];
        d = d * 2 + (p1 > p0 ? 1 : 0);
      }
      dS[c] = d;
    }
    __syncthreads();
    const float step = (float)((1.0 - 1e-8) / 2047.0);
    float v = 0.f;
    for (int c = 0; c < 16; ++c) {
      int mi = i - dS[c];
      if (mi >= 0) {
        float tm = 1e-8f + (float)mi * step;
        float lp = logAS[c] + (kS[c] - 1.0f) * __logf(tm) - rateS[c] * tm;
        v += aS[c] * __expf(lp);
      }
    }
    wsf[OFF_VG + g * 2048 + i] = v;
    float sumsq = v * v;
#pragma unroll
    for (int off = 32; off; off >>= 1) sumsq += __shfl_down(sumsq, off, 64);
    if ((tid & 63) == 0) red[tid >> 6] = sumsq;
    __syncthreads();
    if (tid == 0) wsf[OFF_GSSP + gb] = red[0] + red[1] + red[2] + red[3];
  } else {                               // DHO: 4096 blocks, 4 samples/thread
    int b = bid - 576;
    int rx = b >> 7;
    int t0 = (b & 127) * 1024 + tid * 4;
    __shared__ float pf[40];
    __shared__ float bred[4];
    if (tid < 40) pf[tid] = wsf[OFF_DHP + rx * 40 + tid];
    __syncthreads();
    float sqacc = 0.f;
    unsigned short h4[4];
#pragma unroll
    for (int u = 0; u < 4; ++u) {
      float ttf = (float)(t0 + u) * (10.0f / 131071.0f);
      float o1v = 0.f;
#pragma unroll
      for (int o = 0; o < 2; ++o) {
        float fr = pf[26 + o] * ttf;
        fr -= rintf(fr);
        float sn = __builtin_amdgcn_sinf(fr);
        float cn = __builtin_amdgcn_cosf(fr);
        float ex = __expf(pf[o] * ttf);
        o1v += ex * (pf[6 + o] * cn + pf[24 + o] * sn);
      }
      float prev = o1v, o2v = 0.f, o3v = 0.f;
#pragma unroll
      for (int blk = 1; blk < 3; ++blk) {
        float acc = 0.f;
#pragma unroll
        for (int oo = 0; oo < 2; ++oo) {
          int o = blk * 2 + oo;
          float ng = pf[o];
          float p10 = __expf(prev * pf[18 + o]);
          float rad = __builtin_fmaf(pf[28 + o - 2], p10, -(ng * ng));
          float om = __builtin_amdgcn_sqrtf(rad);
          float fr = (om * INV2PI) * ttf;
          fr -= rintf(fr);
          float sn = __builtin_amdgcn_sinf(fr);
          float cn = __builtin_amdgcn_cosf(fr);
          float Bp = pf[12 + o] * __builtin_amdgcn_rcpf(om);
          float ex = __expf(ng * ttf);
          acc += ex * (pf[6 + o] * cn + Bp * sn);
        }
        if (blk == 1) o2v = acc; else o3v = acc;
        prev = acc;
      }
      float rv = pf[33] * o1v + pf[34] * o2v + pf[35] * o3v;
      h4[u] = f2bf(rv);
      sqacc += rv * rv;
    }
    ushort4v hv;
    hv[0] = h4[0]; hv[1] = h4[1]; hv[2] = h4[2]; hv[3] = h4[3];
    *(ushort4v*)&resb[(size_t)rx * NS + t0] = hv;
#pragma unroll
    for (int off = 32; off; off >>= 1) sqacc += __shfl_down(sqacc, off, 64);
    if ((tid & 63) == 0) bred[tid >> 6] = sqacc;
    __syncthreads();
    if (tid == 0)
      partials[rx * 512 + (b & 127)] = bred[0] + bred[1] + bred[2] + bred[3];
  }
}

// ---------------- B: blocks 0-31 norm reduce; 32-159 impulse; 160-419 abf frags (imp inline)
__global__ __launch_bounds__(256) void kB_mid(
    const float* __restrict__ ovamp, const float* __restrict__ noise,
    float* __restrict__ wsf, unsigned short* __restrict__ abf)
{
  int bid = blockIdx.x;
  int tid = threadIdx.x;
  if (bid < 32) {                        // norm reduce (128 partials per rx)
    int rx = bid;
    const float* partials = wsf + OFF_PART;
    __shared__ float red[4];
    float s = (tid < 128) ? partials[rx * 512 + tid] : 0.f;
#pragma unroll
    for (int off = 32; off; off >>= 1) s += __shfl_down(s, off, 64);
    if ((tid & 63) == 0) red[tid >> 6] = s;
    __syncthreads();
    if (tid == 0) wsf[OFF_NORM + rx] = red[0] + red[1] + red[2] + red[3];
    return;
  }
  __shared__ float wS[8];
  if (tid < 8) {
    float g8 = 0.f;
#pragma unroll
    for (int u = 0; u < 8; ++u) g8 += wsf[OFF_GSSP + tid * 8 + u];
    wS[tid] = 1.0f / (sqrtf(g8) + EPSF);
  }
  __syncthreads();
  const float* vg = wsf + OFF_VG;
  if (bid < 160) {                       // impulse
    int idx0 = bid - 32;
    int c = idx0 >> 3;
    int i = (idx0 & 7) * 256 + tid;
    float S = 0.f;
#pragma unroll
    for (int g = 0; g < 8; ++g) S += vg[g * 2048 + i] * wS[g];
    wsf[OFF_IMP + c * 2048 + i] = ovamp[c] * S * noise[c * 2048 + i];
    return;
  }
  // abf: imp recomputed inline
  int gid = (bid - 160) * 256 + tid;     // 16*65*64 = 66560
  if (gid >= 66560) return;
  int r = gid / (65 * 64);
  int rem = gid % (65 * 64);
  int sc = rem >> 6, lane = rem & 63;
  int m = lane & 15, quad = lane >> 4;
  int qp = (quad < 2) ? quad : quad - 4;
  int base = 32 * sc + m - 8 * qp;
  float oa = ovamp[r];
  short8 v;
#pragma unroll
  for (int j = 0; j < 8; ++j) {
    int idx = base - j;
    unsigned short b = 0;
    if (idx >= 0 && idx < 2048) {
      float S = 0.f;
#pragma unroll
      for (int g = 0; g < 8; ++g) S += vg[g * 2048 + idx] * wS[g];
      b = f2bf(oa * S * noise[r * 2048 + idx]);
    }
    v[j] = (short)b;
  }
  *(short8*)&abf[(size_t)gid * 8] = v;
}

// ---------------- K4: H via MFMA block-Toeplitz, rolling B-frag window; H stored bf16
__global__ __launch_bounds__(256) void k4_mfma(
    const unsigned short* __restrict__ resb, const unsigned short* __restrict__ abf,
    const float* __restrict__ wsf, unsigned short* __restrict__ Hb)
{
  int rx = blockIdx.y, r = rx >> 1;
  int n0 = blockIdx.x * 256;                       // 256 columns of 16 samples
  __shared__ __align__(16) unsigned short Xs[9280]; // 386 cols x stride 24
  int tid = threadIdx.x;
  for (int i = tid; i < 772; i += 256) {           // 16B chunks
    int q_rel = i >> 1, p8 = (i & 1) * 8;
    int q = n0 - 130 + q_rel;
    short8 v = {0, 0, 0, 0, 0, 0, 0, 0};
    if (q >= 0) v = *(const short8*)&resb[(size_t)rx * NS + q * 16 + p8];
    *(short8*)&Xs[q_rel * 24 + p8] = v;
  }
  __syncthreads();
  int lane = tid & 63, w = tid >> 6;
  int quad = lane >> 4, nl = lane & 15;
  float n1 = sqrtf(wsf[OFF_NORM + rx]);
  float s1 = 1.0f / (n1 + EPSF);
  float scale = s1 * (1.0f / (n1 * s1 + EPSF)) * wsf[OFF_MIX1 + r];
  const short8* af = (const short8*)(abf) + (size_t)r * 65 * 64 + lane;
  floatx4 acc0 = {0,0,0,0}, acc1 = {0,0,0,0}, acc2 = {0,0,0,0}, acc3 = {0,0,0,0};
  const char* xbase = (const char*)Xs + (size_t)(130 + w * 64 + nl - (quad >> 1)) * 48
                      + (quad & 1) * 16;
  short8 wbuf[25];
#pragma unroll
  for (int s = -24; s < 0; ++s)
    wbuf[s + 25] = *(const short8*)(xbase - 96 * s);
#pragma unroll
  for (int sc = 0; sc < 65; ++sc) {
    wbuf[sc % 25] = *(const short8*)(xbase - 96 * sc);
    short8 a = af[sc * 64];
    acc0 = __builtin_amdgcn_mfma_f32_16x16x32_bf16(a, wbuf[sc % 25],        acc0, 0, 0, 0);
    acc1 = __builtin_amdgcn_mfma_f32_16x16x32_bf16(a, wbuf[(sc + 17) % 25], acc1, 0, 0, 0);
    acc2 = __builtin_amdgcn_mfma_f32_16x16x32_bf16(a, wbuf[(sc + 9) % 25],  acc2, 0, 0, 0);
    acc3 = __builtin_amdgcn_mfma_f32_16x16x32_bf16(a, wbuf[(sc + 1) % 25],  acc3, 0, 0, 0);
  }
  unsigned short* hp = Hb + (size_t)rx * NS + 16 * (n0 + w * 64 + nl) + quad * 4;
  ushort4v h0, h1, h2, h3;
#pragma unroll
  for (int i = 0; i < 4; ++i) {
    h0[i] = f2bf(acc0[i] * scale);
    h1[i] = f2bf(acc1[i] * scale);
    h2[i] = f2bf(acc2[i] * scale);
    h3[i] = f2bf(acc3[i] * scale);
  }
  *(ushort4v*)(hp)       = h0;
  *(ushort4v*)(hp + 256) = h1;
  *(ushort4v*)(hp + 512) = h2;
  *(ushort4v*)(hp + 768) = h3;
}

// ---------------- K6: 128-tap stride conv via MFMA + deform mix + tanh reduce + cs
// NEW: one block owns an output tile (16 cols x 4 q-rows x mt) for ONE rm and loops
// the 4 rq contributions in-register -> plain stores, no atomics, no zero-init.
__global__ __launch_bounds__(256) void k6_mfma(
    const unsigned short* __restrict__ Hb, const float* __restrict__ imp,
    const unsigned short* __restrict__ abf2,
    const float* __restrict__ wsf, float* __restrict__ out)
{
  int rm = blockIdx.y;                    // 0..3
  int n0 = blockIdx.x * 16;               // 64 col tiles of 16
  int zz = blockIdx.z;                    // mt half
  int tid = threadIdx.x;
  int wm = tid >> 6, lane = tid & 63;
  int quad = lane >> 4, n = lane & 15;
  int col = n0 + n;                       // t' in [0,1024)
  int mt = zz * 4 + wm;                   // 0..7

  __shared__ float fvs2[4][4][128];       // [rq][e][q]
  for (int i = tid; i < 2048; i += 256) {
    int rq = i >> 9, e = (i >> 7) & 3, q = i & 127;
    fvs2[rq][e][q] = wsf[OFF_FV + (e * 16 + rq * 4 + rm) * 128 + q];
  }
  __syncthreads();

  float d0r[4];
  const float* dwg = wsf + OFF_DW;
#pragma unroll
  for (int i = 0; i < 4; ++i) {
    int q = mt * 16 + quad * 4 + i;
    d0r[i] = dwg[q * 1024 + col];
  }

  float tansum[4] = {0.f, 0.f, 0.f, 0.f};
  const short8* af = (const short8*)abf2;

  for (int rq = 0; rq < 4; ++rq) {
    int r = rq * 4 + rm;
    short8 bf0[4], bf1[4];
    const unsigned short* H0 = Hb + (size_t)(2 * r) * NS + col;
    const unsigned short* H1 = Hb + (size_t)(2 * r + 1) * NS + col;
#pragma unroll
    for (int kt = 0; kt < 4; ++kt) {
#pragma unroll
      for (int j = 0; j < 8; ++j) {
        int p = kt * 32 + quad * 8 + j;
        bf0[kt][j] = (short)H0[(size_t)p * 1024];
        bf1[kt][j] = (short)H1[(size_t)p * 1024];
      }
    }
    float impA = imp[r * 2048 + col];
    float impB = imp[r * 2048 + 1024 + col];
    float mix0r = wsf[OFF_MIX0 + r];
    float csum[4] = {0.f, 0.f, 0.f, 0.f};

    for (int e = 0; e < 4; ++e) {
      float ge = wsf[OFF_GABS + 4 * e + rq];
      const short8* afe = af + ((size_t)(r * 4 + e) * 32) * 64 + lane;
      floatx4 acc0 = {0, 0, 0, 0}, acc1 = {0, 0, 0, 0};
#pragma unroll
      for (int kt = 0; kt < 4; ++kt) {
        short8 a = afe[(mt * 4 + kt) * 64];
        acc0 = __builtin_amdgcn_mfma_f32_16x16x32_bf16(a, bf0[kt], acc0, 0, 0, 0);
        acc1 = __builtin_amdgcn_mfma_f32_16x16x32_bf16(a, bf1[kt], acc1, 0, 0, 0);
      }
#pragma unroll
      for (int i = 0; i < 4; ++i) {
        int q = mt * 16 + quad * 4 + i;
        float fq = fvs2[rq][e][q];
        float fqm = (q > 0) ? fvs2[rq][e][q - 1] : 0.f;
        float rsv = fq * impA + fqm * impB;
        csum[i] += rsv;
        float d0 = d0r[i];
        float conv = d0 * acc0[i] + (1.0f - d0) * acc1[i];
        float z = (mix0r * rsv + conv) * ge;
        float e2 = __expf(2.0f * z);
        tansum[i] += 1.0f - 2.0f * __builtin_amdgcn_rcpf(e2 + 1.0f);
      }
    }
#pragma unroll
    for (int i = 0; i < 4; ++i) {
      int q = mt * 16 + quad * 4 + i;
      out[532480 + (size_t)r * NS + q * 1024 + col] = csum[i];
    }
  }
#pragma unroll
  for (int i = 0; i < 4; ++i) {
    int q = mt * 16 + quad * 4 + i;
    out[(size_t)rm * NS + q * 1024 + col] = tansum[i];
  }
}

extern "C" void kernel_launch(void* const* d_in, const int* in_sizes, int n_in,
                              void* d_out, int out_size, void* d_ws, size_t ws_size,
                              hipStream_t stream) {
  const float* csig   = (const float*)d_in[0];
  const float* deform = (const float*)d_in[1];
  const float* aem    = (const float*)d_in[2];
  const float* aes    = (const float*)d_in[3];
  const float* aea    = (const float*)d_in[4];
  const float* aep    = (const float*)d_in[5];
  const float* aeo    = (const float*)d_in[6];
  const float* ddmp   = (const float*)d_in[7];
  const float* dmas   = (const float*)d_in[8];
  const float* dten   = (const float*)d_in[9];
  const float* ddisp  = (const float*)d_in[10];
  const float* damp   = (const float*)d_in[11];
  const float* infl   = (const float*)d_in[12];
  const float* smix   = (const float*)d_in[13];
  const float* router = (const float*)d_in[14];
  const float* lmix   = (const float*)d_in[15];
  const float* gains  = (const float*)d_in[16];
  const float* anoise = (const float*)d_in[17];

  float*  wsf = (float*)d_ws;
  unsigned short* resb = (unsigned short*)d_ws;
  unsigned short* abf  = (unsigned short*)d_ws + AFRAG_USH;
  unsigned short* abf2 = (unsigned short*)d_ws + ABF2_USH;
  unsigned short* Hb   = (unsigned short*)d_ws + HB_USH;
  float*  out = (float*)d_out;

  k0_params<<<1, 256, 0, stream>>>(ddmp, dmas, dten, ddisp, damp, infl, smix, wsf);
  k01_prep_dho<<<4672, 256, 0, stream>>>(csig, deform, smix, router, lmix, gains,
                                         aem, aes, aea, aep, wsf, abf2, resb,
                                         wsf + OFF_PART, out);
  kB_mid<<<420, 256, 0, stream>>>(aeo, anoise, wsf, abf);
  k4_mfma<<<dim3(32, 32), 256, 0, stream>>>(resb, abf, wsf, Hb);
  k6_mfma<<<dim3(64, 4, 2), 256, 0, stream>>>(Hb, wsf + OFF_IMP, abf2, wsf, out);
}

// Round 4
// 160.053 us; speedup vs baseline: 1.0635x; 1.0182x over previous
//
#include <hip/hip_runtime.h>
#include <math.h>

#define NS 131072
#define EPSF 1e-8f

// workspace float offsets
#define OFF_IMP    8388608u  // 16*2048
#define OFF_VG     8421376u  // 8*2048
#define OFF_DW     8437760u  // 131072 deformation ch0 weight
#define OFF_FV     8568832u  // 4*16*128 routed frames
#define OFF_NORM   8577024u  // 32 res sumsq
#define OFF_MIX0   8577064u  // 16
#define OFF_MIX1   8577080u  // 16
#define OFF_GABS   8577096u  // 16
#define OFF_PART   8578560u  // 32*512 per-block norm partials (64 used/rx)
#define OFF_GSSP   8594944u  // 8*8 gauss sumsq partials
#define OFF_DHP    8595200u  // 32*48 precomputed DHO params

// ushort offsets
#define AFRAG_USH  4194304u  // imp A-frags [16 r][65 sc][64 lane][8]
#define ABF2_USH   4726784u  // fv-Toeplitz A-frags [16r][4e][8mt][4kt][64][8]
#define HB_USH     8388608u  // H bf16 [32 rx][131072]

typedef __attribute__((ext_vector_type(8))) short short8;
typedef __attribute__((ext_vector_type(4))) float floatx4;
typedef __attribute__((ext_vector_type(4))) unsigned short ushort4v;
typedef __attribute__((ext_vector_type(4), aligned(4))) float float4u;

#define INV2PI 0.15915494309189535f

__device__ __forceinline__ float sigmf(float x) { return 1.0f / (1.0f + expf(-x)); }

__device__ __forceinline__ unsigned short f2bf(float x) {
  unsigned u = __float_as_uint(x);
  unsigned r = (u + 0x7FFFu + ((u >> 16) & 1u)) >> 16;
  return (unsigned short)r;
}

// ---------------- K0: one block computes all 32 rx DHO params
// pf layout per rx (stride 48): [0..6) -gam | [6..12) amp*x0 | [12..18) gam*amp*x0 |
//   [18..24) infl*ln10 | [24..26) B1p | [26..28) om1/2pi | [28..32) Wf | [33..36) w3 |
//   [36..38) sin(om1*dt) | [38..40) cos(om1*dt) | [40..46) exp(-gam*dt) per osc
__global__ __launch_bounds__(256) void k0_params(
    const float* __restrict__ ddmp, const float* __restrict__ dmas,
    const float* __restrict__ dten, const float* __restrict__ ddisp,
    const float* __restrict__ damp, const float* __restrict__ infl,
    const float* __restrict__ smix, float* __restrict__ wsf)
{
  int tid = threadIdx.x;
  int rx = tid >> 3, ent = tid & 7;
  int r = rx >> 1, x = rx & 1;
  float* g = wsf + OFF_DHP + rx * 48;
  const double dtd = 10.0 / 131071.0;
  if (ent < 6) {
    int bb = ent >> 1, o = ent & 1;
    int id = ((bb * 2 + o) * 16 + r) * 2 + x;
    float mass = 2.0f * sigmf(dmas[id]);
    float gam = 30.0f * sigmf(ddmp[id]) / (2.0f * mass);
    double W = exp((double)dten[id] * 2.302585092994046) / (double)mass;
    float x0v = ddisp[id];
    float ampv = damp[id];
    float infv = 0.f;
    if (bb == 1) infv = infl[(o * 16 + r) * 2 + x];
    if (bb == 2) infv = infl[((2 + o) * 16 + r) * 2 + x];
    g[0 + ent]  = -gam;
    g[6 + ent]  = ampv * x0v;
    g[12 + ent] = gam * ampv * x0v;
    g[18 + ent] = infv * 2.3025851f;
    g[40 + ent] = (float)exp(-(double)gam * dtd);
    if (bb == 0) {
      double om = sqrt(W - (double)gam * (double)gam);
      g[24 + o] = (float)((double)(gam * x0v * ampv) / om);
      g[26 + o] = (float)(om * 0.15915494309189535);
      g[36 + o] = (float)sin(om * dtd);
      g[38 + o] = (float)cos(om * dtd);
    } else {
      g[28 + ent - 2] = (float)W;
    }
    if (ent == 0) { g[32] = 0.f; g[46] = 0.f; g[47] = 0.f; }
  } else if (ent == 6) {
    float a0 = smix[rx * 3], a1 = smix[rx * 3 + 1], a2 = smix[rx * 3 + 2];
    float mm = fmaxf(a0, fmaxf(a1, a2));
    float e0 = expf(a0 - mm), e1 = expf(a1 - mm), e2 = expf(a2 - mm);
    float inv = 1.0f / (e0 + e1 + e2);
    g[33] = e0 * inv; g[34] = e1 * inv; g[35] = e2 * inv;
  }
}

// ---------------- K01: blocks<512: dw, fv/before, abf2, (block0: mixes/gains);
//                  blocks 512-575: gauss -> gss partials;
//                  blocks >=576: DHO chain, 8 samples/thread w/ rotation recurrence
__global__ __launch_bounds__(256) void k01_prep_dho(
    const float* __restrict__ csig, const float* __restrict__ deform,
    const float* __restrict__ smix_unused, const float* __restrict__ router,
    const float* __restrict__ lmix, const float* __restrict__ gains,
    const float* __restrict__ means, const float* __restrict__ stds,
    const float* __restrict__ amps, const float* __restrict__ pos,
    float* __restrict__ wsf, unsigned short* __restrict__ abf2,
    unsigned short* __restrict__ resb, float* __restrict__ partials,
    float* __restrict__ out)
{
  int tid = threadIdx.x;
  int bid = blockIdx.x;
  if (bid < 512) {
    int t = bid * 256 + tid;
    { // deformation softmax + interp weight ch0
      float src = (t + 0.5f) * (1.0f / 1024.0f) - 0.5f;
      src = fminf(fmaxf(src, 0.0f), 127.0f);
      int lo = (int)src;
      int hi = min(lo + 1, 127);
      float w = src - (float)lo;
      float c0l = 1.0f / (1.0f + expf(deform[128 + lo] - (1.0f + deform[lo])));
      float c0h = 1.0f / (1.0f + expf(deform[128 + hi] - (1.0f + deform[hi])));
      wsf[OFF_DW + t] = c0l * (1.0f - w) + c0h * w;
    }
    int mt = bid & 7, e = (bid >> 3) & 3, r = (bid >> 5) & 15;
    __shared__ float fvrow[128];
    if (tid < 128) {
      float s = 0.f;
      for (int c = 0; c < 16; ++c)
        s += csig[(e * 16 + c) * 128 + tid] * router[c * 16 + r];
      fvrow[tid] = s;
      if (mt == 0) {
        wsf[OFF_FV + (e * 16 + r) * 128 + tid] = s;
        out[524288 + (e * 16 + r) * 128 + tid] = s;   // 'before'
      }
    }
    __syncthreads();
    {
      int gid = bid * 256 + tid;
      int lane = gid & 63;
      int kt = (gid >> 6) & 3;
      int m = lane & 15, quad = lane >> 4;
      int base = mt * 16 + m - kt * 32 - quad * 8;
      short8 v;
#pragma unroll
      for (int j = 0; j < 8; ++j) {
        int f = base - j;
        unsigned short b = 0;
        if (f >= 0 && f < 128) b = f2bf(fvrow[f]);
        v[j] = (short)b;
      }
      *(short8*)&abf2[(size_t)gid * 8] = v;
    }
    if (bid == 0 && tid < 16) {
      int r2 = tid;
      float l0 = lmix[r2 * 2], l1 = lmix[r2 * 2 + 1];
      float mx = fmaxf(l0, l1);
      float e0 = expf(l0 - mx), e1 = expf(l1 - mx), inv = 1.0f / (e0 + e1);
      wsf[OFF_MIX0 + r2] = e0 * inv;
      wsf[OFF_MIX1 + r2] = e1 * inv;
      wsf[OFF_GABS + r2] = fabsf(gains[r2]);
    }
  } else if (bid < 576) {                // gauss: 64 blocks
    int gb = bid - 512;
    int g = gb >> 3;
    int i = (gb & 7) * 256 + tid;
    __shared__ float kS[16], rateS[16], logAS[16], aS[16];
    __shared__ int dS[16];
    __shared__ float red[4];
    if (tid < 16) {
      int c = tid, idx = c * 8 + g;
      double m = fabs((double)means[idx]);
      double s = fabs((double)stds[idx]);
      double k = m / (s + 1e-8); k = k * k;
      double rate = m / (s * s + 1e-8);
      double logA = k * log(rate + 1e-8) - lgamma(k);
      kS[c] = (float)k; rateS[c] = (float)rate; logAS[c] = (float)logA;
      aS[c] = fabsf(amps[idx]);
      int d = 0;
      for (int l = 0; l < 11; ++l) {
        float p0 = pos[(idx * 11 + l) * 2], p1 = pos[(idx * 11 + l) * 2 + 1];
        d = d * 2 + (p1 > p0 ? 1 : 0);
      }
      dS[c] = d;
    }
    __syncthreads();
    const float step = (float)((1.0 - 1e-8) / 2047.0);
    float v = 0.f;
    for (int c = 0; c < 16; ++c) {
      int mi = i - dS[c];
      if (mi >= 0) {
        float tm = 1e-8f + (float)mi * step;
        float lp = logAS[c] + (kS[c] - 1.0f) * __logf(tm) - rateS[c] * tm;
        v += aS[c] * __expf(lp);
      }
    }
    wsf[OFF_VG + g * 2048 + i] = v;
    float sumsq = v * v;
#pragma unroll
    for (int off = 32; off; off >>= 1) sumsq += __shfl_down(sumsq, off, 64);
    if ((tid & 63) == 0) red[tid >> 6] = sumsq;
    __syncthreads();
    if (tid == 0) wsf[OFF_GSSP + gb] = red[0] + red[1] + red[2] + red[3];
  } else {                               // DHO: 2048 blocks, 8 samples/thread
    int b = bid - 576;
    int rx = b >> 6;
    int t0 = (b & 63) * 2048 + tid * 8;
    __shared__ float pf[48];
    __shared__ float bred[4];
    if (tid < 48) pf[tid] = wsf[OFF_DHP + rx * 48 + tid];
    __syncthreads();
    const float dtf = 10.0f / 131071.0f;
    float sn1[2], cn1[2], ex1[2], exd[4];
    {
      float ttf0 = (float)t0 * dtf;
#pragma unroll
      for (int o = 0; o < 2; ++o) {
        float fr = pf[26 + o] * ttf0;
        fr -= rintf(fr);
        sn1[o] = __builtin_amdgcn_sinf(fr);
        cn1[o] = __builtin_amdgcn_cosf(fr);
        ex1[o] = __expf(pf[o] * ttf0);
      }
#pragma unroll
      for (int oi = 0; oi < 4; ++oi) exd[oi] = __expf(pf[2 + oi] * ttf0);
    }
    float sqacc = 0.f;
    unsigned short h8[8];
#pragma unroll
    for (int u = 0; u < 8; ++u) {
      float ttf = (float)(t0 + u) * dtf;
      float o1v = ex1[0] * (pf[6] * cn1[0] + pf[24] * sn1[0])
                + ex1[1] * (pf[7] * cn1[1] + pf[25] * sn1[1]);
      float prev = o1v, o2v = 0.f, o3v = 0.f;
#pragma unroll
      for (int blk = 1; blk < 3; ++blk) {
        float acc = 0.f;
#pragma unroll
        for (int oo = 0; oo < 2; ++oo) {
          int o = blk * 2 + oo;
          float ng = pf[o];
          float p10 = __expf(prev * pf[18 + o]);
          float rad = __builtin_fmaf(pf[28 + o - 2], p10, -(ng * ng));
          float om = __builtin_amdgcn_sqrtf(rad);
          float fr = (om * INV2PI) * ttf;
          fr -= rintf(fr);
          float sn = __builtin_amdgcn_sinf(fr);
          float cn = __builtin_amdgcn_cosf(fr);
          float Bp = pf[12 + o] * __builtin_amdgcn_rcpf(om);
          acc += exd[o - 2] * (pf[6 + o] * cn + Bp * sn);
        }
        if (blk == 1) o2v = acc; else o3v = acc;
        prev = acc;
      }
      float rv = pf[33] * o1v + pf[34] * o2v + pf[35] * o3v;
      h8[u] = f2bf(rv);
      sqacc += rv * rv;
      // advance recurrence states for next sample
#pragma unroll
      for (int o = 0; o < 2; ++o) {
        float ns = sn1[o] * pf[38 + o] + cn1[o] * pf[36 + o];
        float nc = cn1[o] * pf[38 + o] - sn1[o] * pf[36 + o];
        sn1[o] = ns; cn1[o] = nc;
        ex1[o] *= pf[40 + o];
      }
#pragma unroll
      for (int oi = 0; oi < 4; ++oi) exd[oi] *= pf[42 + oi];
    }
    short8 hv;
#pragma unroll
    for (int u = 0; u < 8; ++u) hv[u] = (short)h8[u];
    *(short8*)&resb[(size_t)rx * NS + t0] = hv;
#pragma unroll
    for (int off = 32; off; off >>= 1) sqacc += __shfl_down(sqacc, off, 64);
    if ((tid & 63) == 0) bred[tid >> 6] = sqacc;
    __syncthreads();
    if (tid == 0)
      partials[rx * 512 + (b & 63)] = bred[0] + bred[1] + bred[2] + bred[3];
  }
}

// ---------------- B: blocks 0-31 norm reduce; 32-159 impulse; 160-419 abf frags (imp inline)
__global__ __launch_bounds__(256) void kB_mid(
    const float* __restrict__ ovamp, const float* __restrict__ noise,
    float* __restrict__ wsf, unsigned short* __restrict__ abf)
{
  int bid = blockIdx.x;
  int tid = threadIdx.x;
  if (bid < 32) {                        // norm reduce (64 partials per rx)
    int rx = bid;
    const float* partials = wsf + OFF_PART;
    __shared__ float red[4];
    float s = (tid < 64) ? partials[rx * 512 + tid] : 0.f;
#pragma unroll
    for (int off = 32; off; off >>= 1) s += __shfl_down(s, off, 64);
    if ((tid & 63) == 0) red[tid >> 6] = s;
    __syncthreads();
    if (tid == 0) wsf[OFF_NORM + rx] = red[0] + red[1] + red[2] + red[3];
    return;
  }
  __shared__ float wS[8];
  if (tid < 8) {
    float g8 = 0.f;
#pragma unroll
    for (int u = 0; u < 8; ++u) g8 += wsf[OFF_GSSP + tid * 8 + u];
    wS[tid] = 1.0f / (sqrtf(g8) + EPSF);
  }
  __syncthreads();
  const float* vg = wsf + OFF_VG;
  if (bid < 160) {                       // impulse
    int idx0 = bid - 32;
    int c = idx0 >> 3;
    int i = (idx0 & 7) * 256 + tid;
    float S = 0.f;
#pragma unroll
    for (int g = 0; g < 8; ++g) S += vg[g * 2048 + i] * wS[g];
    wsf[OFF_IMP + c * 2048 + i] = ovamp[c] * S * noise[c * 2048 + i];
    return;
  }
  // abf: imp recomputed inline
  int gid = (bid - 160) * 256 + tid;     // 16*65*64 = 66560
  if (gid >= 66560) return;
  int r = gid / (65 * 64);
  int rem = gid % (65 * 64);
  int sc = rem >> 6, lane = rem & 63;
  int m = lane & 15, quad = lane >> 4;
  int qp = (quad < 2) ? quad : quad - 4;
  int base = 32 * sc + m - 8 * qp;
  float oa = ovamp[r];
  short8 v;
  if (base >= 7 && base < 2048) {
    // vectorized: 8 consecutive idx = base-7..base, dwordx4 loads
    float S0 = 0.f, S1 = 0.f, S2 = 0.f, S3 = 0.f, S4 = 0.f, S5 = 0.f, S6 = 0.f, S7 = 0.f;
#pragma unroll
    for (int g = 0; g < 8; ++g) {
      const float* p = vg + g * 2048 + (base - 7);
      float4u a = *(const float4u*)p;
      float4u b2 = *(const float4u*)(p + 4);
      float wg = wS[g];
      S7 = fmaf(a[0], wg, S7);  S6 = fmaf(a[1], wg, S6);
      S5 = fmaf(a[2], wg, S5);  S4 = fmaf(a[3], wg, S4);
      S3 = fmaf(b2[0], wg, S3); S2 = fmaf(b2[1], wg, S2);
      S1 = fmaf(b2[2], wg, S1); S0 = fmaf(b2[3], wg, S0);
    }
    const float* np = noise + r * 2048 + (base - 7);
    float4u na = *(const float4u*)np;
    float4u nb = *(const float4u*)(np + 4);
    v[0] = (short)f2bf(oa * S0 * nb[3]);
    v[1] = (short)f2bf(oa * S1 * nb[2]);
    v[2] = (short)f2bf(oa * S2 * nb[1]);
    v[3] = (short)f2bf(oa * S3 * nb[0]);
    v[4] = (short)f2bf(oa * S4 * na[3]);
    v[5] = (short)f2bf(oa * S5 * na[2]);
    v[6] = (short)f2bf(oa * S6 * na[1]);
    v[7] = (short)f2bf(oa * S7 * na[0]);
  } else {
#pragma unroll
    for (int j = 0; j < 8; ++j) {
      int idx = base - j;
      unsigned short b = 0;
      if (idx >= 0 && idx < 2048) {
        float S = 0.f;
#pragma unroll
        for (int g = 0; g < 8; ++g) S += vg[g * 2048 + idx] * wS[g];
        b = f2bf(oa * S * noise[r * 2048 + idx]);
      }
      v[j] = (short)b;
    }
  }
  *(short8*)&abf[(size_t)gid * 8] = v;
}

// ---------------- K4: H via MFMA block-Toeplitz, rolling B-frag window; H stored bf16
__global__ __launch_bounds__(256) void k4_mfma(
    const unsigned short* __restrict__ resb, const unsigned short* __restrict__ abf,
    const float* __restrict__ wsf, unsigned short* __restrict__ Hb)
{
  int rx = blockIdx.y, r = rx >> 1;
  int n0 = blockIdx.x * 256;                       // 256 columns of 16 samples
  __shared__ __align__(16) unsigned short Xs[9280]; // 386 cols x stride 24
  int tid = threadIdx.x;
  for (int i = tid; i < 772; i += 256) {           // 16B chunks
    int q_rel = i >> 1, p8 = (i & 1) * 8;
    int q = n0 - 130 + q_rel;
    short8 v = {0, 0, 0, 0, 0, 0, 0, 0};
    if (q >= 0) v = *(const short8*)&resb[(size_t)rx * NS + q * 16 + p8];
    *(short8*)&Xs[q_rel * 24 + p8] = v;
  }
  __syncthreads();
  int lane = tid & 63, w = tid >> 6;
  int quad = lane >> 4, nl = lane & 15;
  float n1 = sqrtf(wsf[OFF_NORM + rx]);
  float s1 = 1.0f / (n1 + EPSF);
  float scale = s1 * (1.0f / (n1 * s1 + EPSF)) * wsf[OFF_MIX1 + r];
  const short8* af = (const short8*)(abf) + (size_t)r * 65 * 64 + lane;
  floatx4 acc0 = {0,0,0,0}, acc1 = {0,0,0,0}, acc2 = {0,0,0,0}, acc3 = {0,0,0,0};
  const char* xbase = (const char*)Xs + (size_t)(130 + w * 64 + nl - (quad >> 1)) * 48
                      + (quad & 1) * 16;
  short8 wbuf[25];
#pragma unroll
  for (int s = -24; s < 0; ++s)
    wbuf[s + 25] = *(const short8*)(xbase - 96 * s);
#pragma unroll
  for (int sc = 0; sc < 65; ++sc) {
    wbuf[sc % 25] = *(const short8*)(xbase - 96 * sc);
    short8 a = af[sc * 64];
    acc0 = __builtin_amdgcn_mfma_f32_16x16x32_bf16(a, wbuf[sc % 25],        acc0, 0, 0, 0);
    acc1 = __builtin_amdgcn_mfma_f32_16x16x32_bf16(a, wbuf[(sc + 17) % 25], acc1, 0, 0, 0);
    acc2 = __builtin_amdgcn_mfma_f32_16x16x32_bf16(a, wbuf[(sc + 9) % 25],  acc2, 0, 0, 0);
    acc3 = __builtin_amdgcn_mfma_f32_16x16x32_bf16(a, wbuf[(sc + 1) % 25],  acc3, 0, 0, 0);
  }
  unsigned short* hp = Hb + (size_t)rx * NS + 16 * (n0 + w * 64 + nl) + quad * 4;
  ushort4v h0, h1, h2, h3;
#pragma unroll
  for (int i = 0; i < 4; ++i) {
    h0[i] = f2bf(acc0[i] * scale);
    h1[i] = f2bf(acc1[i] * scale);
    h2[i] = f2bf(acc2[i] * scale);
    h3[i] = f2bf(acc3[i] * scale);
  }
  *(ushort4v*)(hp)       = h0;
  *(ushort4v*)(hp + 256) = h1;
  *(ushort4v*)(hp + 512) = h2;
  *(ushort4v*)(hp + 768) = h3;
}

// ---------------- K6: 128-tap stride conv via MFMA + deform mix + tanh reduce + cs
// one block owns an output tile for ONE rm and loops the 4 rq contributions
// in-register -> plain stores, no atomics, no zero-init.
__global__ __launch_bounds__(256) void k6_mfma(
    const unsigned short* __restrict__ Hb, const float* __restrict__ imp,
    const unsigned short* __restrict__ abf2,
    const float* __restrict__ wsf, float* __restrict__ out)
{
  int rm = blockIdx.y;                    // 0..3
  int n0 = blockIdx.x * 16;               // 64 col tiles of 16
  int zz = blockIdx.z;                    // mt half
  int tid = threadIdx.x;
  int wm = tid >> 6, lane = tid & 63;
  int quad = lane >> 4, n = lane & 15;
  int col = n0 + n;                       // t' in [0,1024)
  int mt = zz * 4 + wm;                   // 0..7

  __shared__ float fvs2[4][4][128];       // [rq][e][q]
  for (int i = tid; i < 2048; i += 256) {
    int rq = i >> 9, e = (i >> 7) & 3, q = i & 127;
    fvs2[rq][e][q] = wsf[OFF_FV + (e * 16 + rq * 4 + rm) * 128 + q];
  }
  __syncthreads();

  float d0r[4];
  const float* dwg = wsf + OFF_DW;
#pragma unroll
  for (int i = 0; i < 4; ++i) {
    int q = mt * 16 + quad * 4 + i;
    d0r[i] = dwg[q * 1024 + col];
  }

  float tansum[4] = {0.f, 0.f, 0.f, 0.f};
  const short8* af = (const short8*)abf2;

  for (int rq = 0; rq < 4; ++rq) {
    int r = rq * 4 + rm;
    short8 bf0[4], bf1[4];
    const unsigned short* H0 = Hb + (size_t)(2 * r) * NS + col;
    const unsigned short* H1 = Hb + (size_t)(2 * r + 1) * NS + col;
#pragma unroll
    for (int kt = 0; kt < 4; ++kt) {
#pragma unroll
      for (int j = 0; j < 8; ++j) {
        int p = kt * 32 + quad * 8 + j;
        bf0[kt][j] = (short)H0[(size_t)p * 1024];
        bf1[kt][j] = (short)H1[(size_t)p * 1024];
      }
    }
    float impA = imp[r * 2048 + col];
    float impB = imp[r * 2048 + 1024 + col];
    float mix0r = wsf[OFF_MIX0 + r];
    float csum[4] = {0.f, 0.f, 0.f, 0.f};

    for (int e = 0; e < 4; ++e) {
      float ge = wsf[OFF_GABS + 4 * e + rq];
      const short8* afe = af + ((size_t)(r * 4 + e) * 32) * 64 + lane;
      floatx4 acc0 = {0, 0, 0, 0}, acc1 = {0, 0, 0, 0};
#pragma unroll
      for (int kt = 0; kt < 4; ++kt) {
        short8 a = afe[(mt * 4 + kt) * 64];
        acc0 = __builtin_amdgcn_mfma_f32_16x16x32_bf16(a, bf0[kt], acc0, 0, 0, 0);
        acc1 = __builtin_amdgcn_mfma_f32_16x16x32_bf16(a, bf1[kt], acc1, 0, 0, 0);
      }
#pragma unroll
      for (int i = 0; i < 4; ++i) {
        int q = mt * 16 + quad * 4 + i;
        float fq = fvs2[rq][e][q];
        float fqm = (q > 0) ? fvs2[rq][e][q - 1] : 0.f;
        float rsv = fq * impA + fqm * impB;
        csum[i] += rsv;
        float d0 = d0r[i];
        float conv = d0 * acc0[i] + (1.0f - d0) * acc1[i];
        float z = (mix0r * rsv + conv) * ge;
        float e2 = __expf(2.0f * z);
        tansum[i] += 1.0f - 2.0f * __builtin_amdgcn_rcpf(e2 + 1.0f);
      }
    }
#pragma unroll
    for (int i = 0; i < 4; ++i) {
      int q = mt * 16 + quad * 4 + i;
      out[532480 + (size_t)r * NS + q * 1024 + col] = csum[i];
    }
  }
#pragma unroll
  for (int i = 0; i < 4; ++i) {
    int q = mt * 16 + quad * 4 + i;
    out[(size_t)rm * NS + q * 1024 + col] = tansum[i];
  }
}

extern "C" void kernel_launch(void* const* d_in, const int* in_sizes, int n_in,
                              void* d_out, int out_size, void* d_ws, size_t ws_size,
                              hipStream_t stream) {
  const float* csig   = (const float*)d_in[0];
  const float* deform = (const float*)d_in[1];
  const float* aem    = (const float*)d_in[2];
  const float* aes    = (const float*)d_in[3];
  const float* aea    = (const float*)d_in[4];
  const float* aep    = (const float*)d_in[5];
  const float* aeo    = (const float*)d_in[6];
  const float* ddmp   = (const float*)d_in[7];
  const float* dmas   = (const float*)d_in[8];
  const float* dten   = (const float*)d_in[9];
  const float* ddisp  = (const float*)d_in[10];
  const float* damp   = (const float*)d_in[11];
  const float* infl   = (const float*)d_in[12];
  const float* smix   = (const float*)d_in[13];
  const float* router = (const float*)d_in[14];
  const float* lmix   = (const float*)d_in[15];
  const float* gains  = (const float*)d_in[16];
  const float* anoise = (const float*)d_in[17];

  float*  wsf = (float*)d_ws;
  unsigned short* resb = (unsigned short*)d_ws;
  unsigned short* abf  = (unsigned short*)d_ws + AFRAG_USH;
  unsigned short* abf2 = (unsigned short*)d_ws + ABF2_USH;
  unsigned short* Hb   = (unsigned short*)d_ws + HB_USH;
  float*  out = (float*)d_out;

  k0_params<<<1, 256, 0, stream>>>(ddmp, dmas, dten, ddisp, damp, infl, smix, wsf);
  k01_prep_dho<<<2624, 256, 0, stream>>>(csig, deform, smix, router, lmix, gains,
                                         aem, aes, aea, aep, wsf, abf2, resb,
                                         wsf + OFF_PART, out);
  kB_mid<<<420, 256, 0, stream>>>(aeo, anoise, wsf, abf);
  k4_mfma<<<dim3(32, 32), 256, 0, stream>>>(resb, abf, wsf, Hb);
  k6_mfma<<<dim3(64, 4, 2), 256, 0, stream>>>(Hb, wsf + OFF_IMP, abf2, wsf, out);
}